// Round 17
// baseline (496.215 us; speedup 1.0000x reference)
//
#include <hip/hip_runtime.h>
#include <hip/hip_bf16.h>
#include <cstdint>
#include <cstddef>

#define NND 50000
#define DIN 1488
#define DINP 1536
#define DHID 1024
#define DOUT 512
#define DHC 256
#define NE 800000
#define NHD 8

typedef __attribute__((ext_vector_type(8))) short short8;
typedef __attribute__((ext_vector_type(4))) short short4v;
typedef __attribute__((ext_vector_type(4))) float f32x4;
typedef __attribute__((ext_vector_type(4))) int int4v;
typedef unsigned short ushort_t;

__device__ __forceinline__ unsigned short f2bf(float f){
  union { float f; unsigned u; } v; v.f = f;
  unsigned r = v.u + 0x7fffu + ((v.u >> 16) & 1u);
  return (unsigned short)(r >> 16);
}
__device__ __forceinline__ float bf2f(unsigned short u){
  union { unsigned u; float f; } v; v.u = ((unsigned)u) << 16;
  return v.f;
}

__device__ __forceinline__ void async16(const void* g, void* l){
  __builtin_amdgcn_global_load_lds((__attribute__((address_space(1))) void*)g,
                                   (__attribute__((address_space(3))) void*)l, 16, 0, 0);
}

// ---- fused stage 1: count_edges(x4) + LN (1-pass, 16B stores) + prep -------
__device__ __forceinline__ void tc_tile(const float* __restrict__ W,
                                        ushort_t* __restrict__ WT,
                                        int K, int Nn, int Kp, int bx, int by){
  __shared__ float tile[32][33];
  const int tx = threadIdx.x & 31, ty = threadIdx.x >> 5;
  const int k0 = bx*32, n0 = by*32;
  for (int i = ty; i < 32; i += 8){
    int k = k0 + i, n = n0 + tx;
    tile[i][tx] = (k < K && n < Nn) ? W[(size_t)k*Nn + n] : 0.f;
  }
  __syncthreads();
  for (int i = ty; i < 32; i += 8){
    int n = n0 + i, k = k0 + tx;
    if (n < Nn && k < Kp) WT[(size_t)n*Kp + k] = f2bf(tile[tx][i]);
  }
}

#define F1_CNT  782
#define F1_LN   (F1_CNT + 12500)
__global__ __launch_bounds__(256) void fused1(const float* __restrict__ x,
                                              const float* __restrict__ gw,
                                              const float* __restrict__ bw,
                                              ushort_t* __restrict__ xn,
                                              const int* __restrict__ ei,
                                              int* __restrict__ cnt,
                                              const float* W1, const float* Wr,
                                              const float* Wg, const float* W2,
                                              const float* b2, const float* br,
                                              ushort_t* W1T, ushort_t* WrgT,
                                              ushort_t* W2bf, float* b2rg){
  const int bid = blockIdx.x;
  if (bid < F1_CNT){
    int i4 = bid*256 + threadIdx.x;
    if (i4 < NE/4){
      int4v v = *(const int4v*)(ei + NE + i4*4);
      atomicAdd(&cnt[v.x], 1); atomicAdd(&cnt[v.y], 1);
      atomicAdd(&cnt[v.z], 1); atomicAdd(&cnt[v.w], 1);
    }
    return;
  }
  if (bid < F1_LN){
    const int wid = threadIdx.x >> 6, lane = threadIdx.x & 63;
    const int row = (bid - F1_CNT)*4 + wid;
    if (row >= NND) return;
    const float* xr = x + (size_t)row * DIN;
    f32x4 xa[3], xb[3];
    float s = 0.f, sq = 0.f;
    #pragma unroll
    for (int it = 0; it < 3; ++it){
      const int i = lane*8 + it*512;
      if (i < DIN){
        xa[it] = *(const f32x4*)(xr + i);
        xb[it] = *(const f32x4*)(xr + i + 4);
      } else {
        xa[it] = (f32x4){0.f,0.f,0.f,0.f};
        xb[it] = (f32x4){0.f,0.f,0.f,0.f};
      }
      s  += xa[it].x + xa[it].y + xa[it].z + xa[it].w
          + xb[it].x + xb[it].y + xb[it].z + xb[it].w;
      sq += xa[it].x*xa[it].x + xa[it].y*xa[it].y + xa[it].z*xa[it].z + xa[it].w*xa[it].w
          + xb[it].x*xb[it].x + xb[it].y*xb[it].y + xb[it].z*xb[it].z + xb[it].w*xb[it].w;
    }
    #pragma unroll
    for (int o = 32; o; o >>= 1){ s += __shfl_xor(s, o); sq += __shfl_xor(sq, o); }
    const float mu = s * (1.f/DIN);
    const float var = sq * (1.f/DIN) - mu*mu;
    const float rstd = rsqrtf(var + 1e-5f);
    ushort_t* xo = xn + (size_t)row * DINP;
    #pragma unroll
    for (int it = 0; it < 3; ++it){
      const int i = lane*8 + it*512;
      union { ushort_t u[8]; short8 v; } o;
      if (i < DIN){
        f32x4 ga = *(const f32x4*)(gw + i);
        f32x4 gb = *(const f32x4*)(gw + i + 4);
        f32x4 ba = *(const f32x4*)(bw + i);
        f32x4 bb = *(const f32x4*)(bw + i + 4);
        o.u[0] = f2bf((xa[it].x-mu)*rstd*ga.x + ba.x);
        o.u[1] = f2bf((xa[it].y-mu)*rstd*ga.y + ba.y);
        o.u[2] = f2bf((xa[it].z-mu)*rstd*ga.z + ba.z);
        o.u[3] = f2bf((xa[it].w-mu)*rstd*ga.w + ba.w);
        o.u[4] = f2bf((xb[it].x-mu)*rstd*gb.x + bb.x);
        o.u[5] = f2bf((xb[it].y-mu)*rstd*gb.y + bb.y);
        o.u[6] = f2bf((xb[it].z-mu)*rstd*gb.z + bb.z);
        o.u[7] = f2bf((xb[it].w-mu)*rstd*gb.w + bb.w);
      } else {
        o.u[0]=o.u[1]=o.u[2]=o.u[3]=o.u[4]=o.u[5]=o.u[6]=o.u[7]=0;
      }
      *(short8*)(xo + i) = o.v;
    }
    return;
  }
  {
    int b = bid - F1_LN;
    if (b < 1536){ tc_tile(W1, W1T, DIN, DHID, DINP, b % 48, b / 48); return; }
    b -= 1536;
    if (b < 128){ tc_tile(Wr, WrgT, DOUT, DHC, DOUT, b % 16, b / 16); return; }
    b -= 128;
    if (b < 128){ tc_tile(Wg, WrgT + 256*DOUT, DOUT, DHC, DOUT, b % 16, b / 16); return; }
    b -= 128;
    if (b < 256){
      const int idx = (b*256 + threadIdx.x)*8;
      f32x4 v0 = *(const f32x4*)(W2 + idx);
      f32x4 v1 = *(const f32x4*)(W2 + idx + 4);
      union { ushort_t u[8]; short8 s; } o;
      o.u[0]=f2bf(v0.x); o.u[1]=f2bf(v0.y); o.u[2]=f2bf(v0.z); o.u[3]=f2bf(v0.w);
      o.u[4]=f2bf(v1.x); o.u[5]=f2bf(v1.y); o.u[6]=f2bf(v1.z); o.u[7]=f2bf(v1.w);
      *(short8*)(W2bf + idx) = o.s;
      return;
    }
    b -= 256;
    {
      const int c = b*256 + threadIdx.x;
      float acc = 0.f;
      if (c < 256){
        for (int j = 0; j < DOUT; ++j) acc += b2[j]*Wr[(size_t)j*DHC + c];
        acc += br[c];
      } else {
        const int cc = c - 256;
        for (int j = 0; j < DOUT; ++j) acc += b2[j]*Wg[(size_t)j*DHC + cc];
      }
      b2rg[c] = acc;
      return;
    }
  }
}

// ------- 256x256 8-phase GEMM body (device fn; runtime act; bf16 out) -------
__device__ __forceinline__ void g256p8_body(ushort_t (&lds)[2][2][2][64*128],
                                            const ushort_t* __restrict__ A,
                                            const ushort_t* __restrict__ BT,
                                            const float* __restrict__ bias,
                                            ushort_t* __restrict__ out0,
                                            int M, int Nn, int K,
                                            int bid, int nwg, bool act){
  const int t = threadIdx.x, wid = t >> 6, lane = t & 63;
  const int CB = Nn >> 8;
  const int q = nwg >> 3, r = nwg & 7;
  const int xcd = bid & 7, slot = bid >> 3;
  const int lg = (xcd < r ? xcd*(q+1) : r*(q+1) + (xcd - r)*q) + slot;
  const int brow = (lg / CB) * 256, bcol = (lg % CB) * 256;

  const int l8  = t >> 3;
  const int cb  = (t & 7) << 4;
  const unsigned scb = (unsigned)(cb ^ ((l8 & 7) << 4));
  unsigned rowA[2][2], rowB[2][2];
  #pragma unroll
  for (int hf = 0; hf < 2; ++hf)
    #pragma unroll
    for (int rd = 0; rd < 2; ++rd){
      int ra = brow + hf*128 + rd*64 + l8; ra = ra < M ? ra : M-1;
      int rb = bcol + hf*128 + rd*64 + l8; rb = rb < Nn ? rb : Nn-1;
      rowA[hf][rd] = (unsigned)ra * (unsigned)(K*2);
      rowB[hf][rd] = (unsigned)rb * (unsigned)(K*2);
    }
  const int w8 = wid * 8;

#define STG_A(buf, hf, kt) do {                                               \
    const unsigned _ob = (unsigned)(kt)*128u + scb;                           \
    async16((const char*)A + rowA[hf][0] + _ob, &lds[buf][0][hf][(w8)*64]);   \
    async16((const char*)A + rowA[hf][1] + _ob, &lds[buf][0][hf][(64+w8)*64]);\
  } while(0)
#define STG_B(buf, hf, kt) do {                                               \
    const unsigned _ob = (unsigned)(kt)*128u + scb;                           \
    async16((const char*)BT + rowB[hf][0] + _ob, &lds[buf][1][hf][(w8)*64]);  \
    async16((const char*)BT + rowB[hf][1] + _ob, &lds[buf][1][hf][(64+w8)*64]);\
  } while(0)

  f32x4 acc[8][4];
  #pragma unroll
  for (int i=0;i<8;i++)
    #pragma unroll
    for (int j=0;j<4;j++) acc[i][j] = (f32x4){0.f,0.f,0.f,0.f};

  const int wrow = (wid >> 2), wcol = (wid & 3);
  const int fr = lane & 15;
  const int kb0 = (lane >> 4) << 4;
  const int sx  = (fr & 7) << 4;
  const int ko0 = ((kb0      ) ^ sx) >> 1;
  const int ko1 = ((kb0 | 64 ) ^ sx) >> 1;
  const int bhalf = wcol >> 1, brl = (wcol & 1)*64;

#define RD_A(buf, m) do {                                          \
    const int _ra = ((m)*16 + fr)*64;                              \
    af[m][0] = *(const short8*)&lds[buf][0][wrow][_ra + ko0];      \
    af[m][1] = *(const short8*)&lds[buf][0][wrow][_ra + ko1];      \
  } while(0)
#define RD_B(buf, n) do {                                          \
    const int _rb = (brl + (n)*16 + fr)*64;                        \
    bf[n][0] = *(const short8*)&lds[buf][1][bhalf][_rb + ko0];     \
    bf[n][1] = *(const short8*)&lds[buf][1][bhalf][_rb + ko1];     \
  } while(0)
#define SYNC_PH() do {                                             \
    __builtin_amdgcn_s_barrier();                                  \
    asm volatile("s_waitcnt lgkmcnt(0)" ::: "memory");             \
    __builtin_amdgcn_sched_barrier(0);                             \
  } while(0)
#define MFMA_Q(M0, N0) do {                                        \
    __builtin_amdgcn_s_setprio(1);                                 \
    _Pragma("unroll")                                              \
    for (int _m=(M0); _m<(M0)+4; ++_m)                             \
      _Pragma("unroll")                                            \
      for (int _n=(N0); _n<(N0)+2; ++_n){                          \
        acc[_m][_n] = __builtin_amdgcn_mfma_f32_16x16x32_bf16(af[_m][0], bf[_n][0], acc[_m][_n], 0, 0, 0); \
        acc[_m][_n] = __builtin_amdgcn_mfma_f32_16x16x32_bf16(af[_m][1], bf[_n][1], acc[_m][_n], 0, 0, 0); \
      }                                                            \
    __builtin_amdgcn_s_setprio(0);                                 \
  } while(0)

  const int nk = K >> 6;
  STG_A(0,0,0); STG_A(0,1,0); STG_B(0,0,0); STG_B(0,1,0);
  STG_A(1,0,1); STG_A(1,1,1);
  asm volatile("s_waitcnt vmcnt(4)" ::: "memory");
  __builtin_amdgcn_s_barrier();

  for (int kt = 0; kt < nk; ++kt){
    const int buf = kt & 1, obuf = buf ^ 1;
    short8 af[8][2], bf[4][2];
    RD_A(buf,0); RD_A(buf,1); RD_A(buf,2); RD_A(buf,3);
    RD_B(buf,0); RD_B(buf,1);
    if (kt + 1 < nk) STG_B(obuf, 0, kt + 1);
    SYNC_PH();
    MFMA_Q(0, 0);
    RD_A(buf,4); RD_A(buf,5); RD_A(buf,6); RD_A(buf,7);
    if (kt + 1 < nk) STG_B(obuf, 1, kt + 1);
    SYNC_PH();
    MFMA_Q(4, 0);
    RD_B(buf,2); RD_B(buf,3);
    if (kt + 2 < nk) STG_A(buf, 0, kt + 2);
    SYNC_PH();
    MFMA_Q(0, 2);
    if (kt + 2 < nk){
      STG_A(buf, 1, kt + 2);
      asm volatile("s_waitcnt vmcnt(4)" ::: "memory");
    } else {
      asm volatile("s_waitcnt vmcnt(0)" ::: "memory");
    }
    __builtin_amdgcn_s_barrier();
    MFMA_Q(4, 2);
  }
#undef STG_A
#undef STG_B
#undef RD_A
#undef RD_B
#undef SYNC_PH
#undef MFMA_Q

  float bv[4];
  #pragma unroll
  for (int n=0;n<4;n++){
    const int col = bcol + wcol*64 + n*16 + (lane & 15);
    bv[n] = bias ? bias[col] : 0.f;
  }
  ushort_t* sB = (ushort_t*)&lds[0][0][0][0];
  __syncthreads();
  #pragma unroll
  for (int m=0;m<8;m++){
    const int row = wrow*128 + m*16 + (lane >> 4)*4;
    #pragma unroll
    for (int n=0;n<4;n++){
      const int col = wcol*64 + n*16 + (lane & 15);
      #pragma unroll
      for (int j=0;j<4;j++){
        float v = acc[m][n][j] + bv[n];
        if (act) v = v > 0.f ? v : 0.f;
        sB[(row+j)*256 + col] = f2bf(v);
      }
    }
  }
  __syncthreads();
  const int srow = t >> 5, scol8 = (t & 31) * 8;
  #pragma unroll
  for (int rr = 0; rr < 16; ++rr){
    const int rloc = rr*16 + srow;
    const int grow = brow + rloc;
    if (grow < M)
      *(short8*)(out0 + (size_t)grow*Nn + bcol + scol8) = *(const short8*)&sB[rloc*256 + scol8];
  }
}

// ---- k2 mega kernel: GEMM1 (blk 0-783) + scan (784) + WcT (785-792) --------
#define G1_NWG 784
__global__ __launch_bounds__(512, 1) void mega_gemm(const ushort_t* __restrict__ xn,
                                                    const ushort_t* __restrict__ W1T,
                                                    const float* __restrict__ b1,
                                                    ushort_t* __restrict__ h1,
                                                    const ushort_t* __restrict__ WrgT,
                                                    const ushort_t* __restrict__ W2bf,
                                                    ushort_t* __restrict__ WcT,
                                                    const int* __restrict__ cnt,
                                                    int* __restrict__ offs,
                                                    int* __restrict__ cur){
  __shared__ __align__(16) ushort_t lds[2][2][2][64*128];  // 128 KiB
  const int t = threadIdx.x;

  if (blockIdx.x == G1_NWG){
    int* sbuf = (int*)&lds[0][0][0][0];
    const int chunk = (NND + 255) >> 8;                  // 196, mult of 4
    int s = 0;
    if (t < 256){
      const int s0 = t*chunk;
      const int s1 = (s0 + chunk < NND) ? s0 + chunk : NND;
      for (int i = s0; i < s1; i += 4){
        int4v v = *(const int4v*)(cnt + i);
        s += v.x + v.y + v.z + v.w + 4;
      }
    }
    sbuf[t] = s; __syncthreads();
    for (int o = 1; o < 256; o <<= 1){
      int xv = (t >= o && t < 256) ? sbuf[t-o] : 0;
      __syncthreads();
      if (t < 256) sbuf[t] += xv;
      __syncthreads();
    }
    if (t < 256){
      int run = sbuf[t] - s;
      const int s0 = t*chunk;
      const int s1 = (s0 + chunk < NND) ? s0 + chunk : NND;
      for (int i = s0; i < s1; i += 4){
        int4v v = *(const int4v*)(cnt + i);
        int4v cu;
        cu.x = run; run += v.x + 1;
        cu.y = run; run += v.y + 1;
        cu.z = run; run += v.z + 1;
        cu.w = run; run += v.w + 1;
        *(int4v*)(cur + i)  = cu;
        *(int4v*)(offs + i) = cu;
      }
      if (t == 255) offs[NND] = run;
    }
    return;
  }
  if (blockIdx.x > G1_NWG){
    g256p8_body(lds, WrgT, W2bf, nullptr, WcT, 512, 1024, 512,
                (int)blockIdx.x - (G1_NWG + 1), 8, false);
    return;
  }
  g256p8_body(lds, xn, W1T, b1, h1, NND, DHID, DINP,
              (int)blockIdx.x, G1_NWG, true);
}

// ---- k3: 8-phase GEMM [res|gm] = h1 @ WcT^T + b2rg, split epilogue + att ---
#define G3_NWG 392
__global__ __launch_bounds__(512, 1) void gemm3p8(const ushort_t* __restrict__ A,
                                                  const ushort_t* __restrict__ BT,
                                                  const float* __restrict__ bias,
                                                  float* __restrict__ res,
                                                  ushort_t* __restrict__ gm,
                                                  const int* __restrict__ ei,
                                                  int* __restrict__ cur,
                                                  int* __restrict__ eidx,
                                                  const float* __restrict__ att_s,
                                                  const float* __restrict__ att_d,
                                                  float* __restrict__ asrc,
                                                  float* __restrict__ adst){
  __shared__ __align__(16) ushort_t lds[2][2][2][64*128];  // 128 KiB
  const int t = threadIdx.x, wid = t >> 6, lane = t & 63;

  if (blockIdx.x >= G3_NWG){
    int i = (blockIdx.x - G3_NWG)*512 + t;
    if (i < NND){
      int p = atomicAdd(&cur[i], 1); eidx[p] = i;
    } else if (i < NND + NE){
      int e = i - NND;
      int src = ei[e], dst = ei[NE + e];
      int p = atomicAdd(&cur[dst], 1);
      eidx[p] = src;
    }
    return;
  }

  const int M = NND, Nn = 512, K = DHID;
  const int bid = blockIdx.x, nwg = G3_NWG;
  const int CB = 2;
  const int q = nwg >> 3, r = nwg & 7;
  const int xcd = bid & 7, slot = bid >> 3;
  const int lg = (xcd < r ? xcd*(q+1) : r*(q+1) + (xcd - r)*q) + slot;
  const int brow = (lg / CB) * 256, bcol = (lg % CB) * 256;

  const int l8  = t >> 3;
  const int cb  = (t & 7) << 4;
  const unsigned scb = (unsigned)(cb ^ ((l8 & 7) << 4));
  unsigned rowA[2][2], rowB[2][2];
  #pragma unroll
  for (int hf = 0; hf < 2; ++hf)
    #pragma unroll
    for (int rd = 0; rd < 2; ++rd){
      int ra = brow + hf*128 + rd*64 + l8; ra = ra < M ? ra : M-1;
      int rb = bcol + hf*128 + rd*64 + l8; rb = rb < Nn ? rb : Nn-1;
      rowA[hf][rd] = (unsigned)ra * (unsigned)(K*2);
      rowB[hf][rd] = (unsigned)rb * (unsigned)(K*2);
    }
  const int w8 = wid * 8;

#define STG_A(buf, hf, kt) do {                                               \
    const unsigned _ob = (unsigned)(kt)*128u + scb;                           \
    async16((const char*)A + rowA[hf][0] + _ob, &lds[buf][0][hf][(w8)*64]);   \
    async16((const char*)A + rowA[hf][1] + _ob, &lds[buf][0][hf][(64+w8)*64]);\
  } while(0)
#define STG_B(buf, hf, kt) do {                                               \
    const unsigned _ob = (unsigned)(kt)*128u + scb;                           \
    async16((const char*)BT + rowB[hf][0] + _ob, &lds[buf][1][hf][(w8)*64]);  \
    async16((const char*)BT + rowB[hf][1] + _ob, &lds[buf][1][hf][(64+w8)*64]);\
  } while(0)

  f32x4 acc[8][4];
  #pragma unroll
  for (int i=0;i<8;i++)
    #pragma unroll
    for (int j=0;j<4;j++) acc[i][j] = (f32x4){0.f,0.f,0.f,0.f};

  const int wrow = (wid >> 2), wcol = (wid & 3);
  const int fr = lane & 15;
  const int kb0 = (lane >> 4) << 4;
  const int sx  = (fr & 7) << 4;
  const int ko0 = ((kb0      ) ^ sx) >> 1;
  const int ko1 = ((kb0 | 64 ) ^ sx) >> 1;
  const int bhalf = wcol >> 1, brl = (wcol & 1)*64;

#define RD_A(buf, m) do {                                          \
    const int _ra = ((m)*16 + fr)*64;                              \
    af[m][0] = *(const short8*)&lds[buf][0][wrow][_ra + ko0];      \
    af[m][1] = *(const short8*)&lds[buf][0][wrow][_ra + ko1];      \
  } while(0)
#define RD_B(buf, n) do {                                          \
    const int _rb = (brl + (n)*16 + fr)*64;                        \
    bf[n][0] = *(const short8*)&lds[buf][1][bhalf][_rb + ko0];     \
    bf[n][1] = *(const short8*)&lds[buf][1][bhalf][_rb + ko1];     \
  } while(0)
#define SYNC_PH() do {                                             \
    __builtin_amdgcn_s_barrier();                                  \
    asm volatile("s_waitcnt lgkmcnt(0)" ::: "memory");             \
    __builtin_amdgcn_sched_barrier(0);                             \
  } while(0)
#define MFMA_Q(M0, N0) do {                                        \
    __builtin_amdgcn_s_setprio(1);                                 \
    _Pragma("unroll")                                              \
    for (int _m=(M0); _m<(M0)+4; ++_m)                             \
      _Pragma("unroll")                                            \
      for (int _n=(N0); _n<(N0)+2; ++_n){                          \
        acc[_m][_n] = __builtin_amdgcn_mfma_f32_16x16x32_bf16(af[_m][0], bf[_n][0], acc[_m][_n], 0, 0, 0); \
        acc[_m][_n] = __builtin_amdgcn_mfma_f32_16x16x32_bf16(af[_m][1], bf[_n][1], acc[_m][_n], 0, 0, 0); \
      }                                                            \
    __builtin_amdgcn_s_setprio(0);                                 \
  } while(0)

  const int nk = K >> 6;
  STG_A(0,0,0); STG_A(0,1,0); STG_B(0,0,0); STG_B(0,1,0);
  STG_A(1,0,1); STG_A(1,1,1);
  asm volatile("s_waitcnt vmcnt(4)" ::: "memory");
  __builtin_amdgcn_s_barrier();

  for (int kt = 0; kt < nk; ++kt){
    const int buf = kt & 1, obuf = buf ^ 1;
    short8 af[8][2], bf[4][2];
    RD_A(buf,0); RD_A(buf,1); RD_A(buf,2); RD_A(buf,3);
    RD_B(buf,0); RD_B(buf,1);
    if (kt + 1 < nk) STG_B(obuf, 0, kt + 1);
    SYNC_PH();
    MFMA_Q(0, 0);
    RD_A(buf,4); RD_A(buf,5); RD_A(buf,6); RD_A(buf,7);
    if (kt + 1 < nk) STG_B(obuf, 1, kt + 1);
    SYNC_PH();
    MFMA_Q(4, 0);
    RD_B(buf,2); RD_B(buf,3);
    if (kt + 2 < nk) STG_A(buf, 0, kt + 2);
    SYNC_PH();
    MFMA_Q(0, 2);
    if (kt + 2 < nk){
      STG_A(buf, 1, kt + 2);
      asm volatile("s_waitcnt vmcnt(4)" ::: "memory");
    } else {
      asm volatile("s_waitcnt vmcnt(0)" ::: "memory");
    }
    __builtin_amdgcn_s_barrier();
    MFMA_Q(4, 2);
  }
#undef STG_A
#undef STG_B
#undef RD_A
#undef RD_B
#undef SYNC_PH
#undef MFMA_Q

  float bv[4];
  #pragma unroll
  for (int n=0;n<4;n++){
    const int col = bcol + wcol*64 + n*16 + (lane & 15);
    bv[n] = bias[col];
  }
  if (bcol == 0){
    float* sF = (float*)&lds[0][0][0][0];            // [128][256] f32
    #pragma unroll
    for (int p = 0; p < 2; ++p){
      __syncthreads();
      if (wrow == p){
        #pragma unroll
        for (int m=0;m<8;m++){
          const int row = m*16 + (lane >> 4)*4;
          #pragma unroll
          for (int n=0;n<4;n++){
            const int col = wcol*64 + n*16 + (lane & 15);
            #pragma unroll
            for (int j=0;j<4;j++)
              sF[(row+j)*256 + col] = acc[m][n][j] + bv[n];
          }
        }
      }
      __syncthreads();
      const int srow = t >> 6, scol4 = (t & 63) * 4;
      #pragma unroll
      for (int rr = 0; rr < 16; ++rr){
        const int rloc = rr*8 + srow;
        const int grow = brow + p*128 + rloc;
        if (grow < M)
          *(f32x4*)(res + (size_t)grow*256 + scol4) = *(const f32x4*)&sF[rloc*256 + scol4];
      }
    }
  } else {
    ushort_t* sB = (ushort_t*)&lds[0][0][0][0];      // [256][256] bf16
    __syncthreads();
    #pragma unroll
    for (int m=0;m<8;m++){
      const int row = wrow*128 + m*16 + (lane >> 4)*4;
      #pragma unroll
      for (int n=0;n<4;n++){
        const int col = wcol*64 + n*16 + (lane & 15);
        #pragma unroll
        for (int j=0;j<4;j++)
          sB[(row+j)*256 + col] = f2bf(acc[m][n][j] + bv[n]);
      }
    }
    __syncthreads();
    const int srow = t >> 5, scol8 = (t & 31) * 8;
    #pragma unroll
    for (int rr = 0; rr < 16; ++rr){
      const int rloc = rr*16 + srow;
      const int grow = brow + rloc;
      if (grow < M)
        *(short8*)(gm + (size_t)grow*256 + scol8) = *(const short8*)&sB[rloc*256 + scol8];
    }
    const int h = t & 7;
    const int hc0 = h * 32;
    #pragma unroll
    for (int k = 0; k < 4; ++k){
      const int rloc = (t >> 3) + k*64;
      const int grow = brow + rloc;
      if (grow < M){
        float a = 0.f, d = 0.f;
        #pragma unroll
        for (int c0 = 0; c0 < 32; c0 += 8){
          short8 gv = *(const short8*)&sB[rloc*256 + hc0 + c0];
          #pragma unroll
          for (int j = 0; j < 8; ++j){
            float g = bf2f((ushort_t)gv[j]);
            a += g*att_s[hc0 + c0 + j];
            d += g*att_d[hc0 + c0 + j];
          }
        }
        asrc[grow*NHD + h] = a;
        adst[grow*NHD + h] = d;
      }
    }
  }
}

// ---- fused GAT aggregate (wave/node, 8-edge chunks, 2-deep pipeline) ------
__global__ __launch_bounds__(256) void gat_agg(const int* __restrict__ offs,
                                               const int* __restrict__ eidx,
                                               const float* __restrict__ asrc,
                                               const float* __restrict__ adst,
                                               const ushort_t* __restrict__ gm,
                                               const float* __restrict__ res,
                                               const float* __restrict__ bg,
                                               float* __restrict__ out){
  const int wid = threadIdx.x >> 6, lane = threadIdx.x & 63;
  const int node = blockIdx.x*4 + wid;
  if (node >= NND) return;
  const int h = lane >> 3, jj = lane & 7;
  const int e0 = offs[node], deg = offs[node+1] - e0;
  const float adv = adst[node*NHD + h];

  float mx = -1e30f;
  for (int j = jj; j < deg; j += 8){
    int s = eidx[e0 + j];
    float e = asrc[s*NHD + h] + adv; e = e > 0.f ? e : 0.2f*e;
    mx = fmaxf(mx, e);
  }
  mx = fmaxf(mx, __shfl_xor(mx, 1));
  mx = fmaxf(mx, __shfl_xor(mx, 2));
  mx = fmaxf(mx, __shfl_xor(mx, 4));

  const int c4 = lane*4;
  float sm = 0.f;
  f32x4 acc = {0.f,0.f,0.f,0.f};

  // prologue: chunk 0 weights
  int s = 0; float w = 0.f;
  {
    const int cnt0 = deg < 8 ? deg : 8;
    if (jj < cnt0){
      s = eidx[e0 + jj];
      float e = asrc[s*NHD + h] + adv; e = e > 0.f ? e : 0.2f*e;
      w = __expf(e - mx);
      sm += w;
    }
  }
  for (int j0 = 0; j0 < deg; j0 += 8){
    const int cnt = (deg - j0) < 8 ? (deg - j0) : 8;
    // prefetch next chunk's weight chain while gathering this chunk
    int ns = 0; float nw = 0.f;
    const int ncnt = (deg - j0 - 8) < 8 ? (deg - j0 - 8) : 8;
    if (jj < ncnt){
      ns = eidx[e0 + j0 + 8 + jj];
      float e = asrc[ns*NHD + h] + adv; e = e > 0.f ? e : 0.2f*e;
      nw = __expf(e - mx);
      sm += nw;
    }
    #pragma unroll
    for (int u = 0; u < 8; ++u){
      if (u < cnt){
        const int   su = __builtin_amdgcn_readlane(s, u);
        const float wu = __shfl(w, (h << 3) | u);
        short4v gv = *(const short4v*)(gm + (size_t)su*DHC + c4);
        acc.x += wu*bf2f((ushort_t)gv.x);
        acc.y += wu*bf2f((ushort_t)gv.y);
        acc.z += wu*bf2f((ushort_t)gv.z);
        acc.w += wu*bf2f((ushort_t)gv.w);
      }
    }
    s = ns; w = nw;
  }
  sm += __shfl_xor(sm, 1); sm += __shfl_xor(sm, 2); sm += __shfl_xor(sm, 4);
  const float inv = 1.f/(sm + 1e-16f);

  f32x4 bgv = *(const f32x4*)(bg + c4);
  f32x4 rv  = *(const f32x4*)(res + (size_t)node*DHC + c4);
  f32x4 o;
  #pragma unroll
  for (int q = 0; q < 4; ++q){
    float v = acc[q]*inv + bgv[q];
    v = v > 0.f ? v : expm1f(v);
    o[q] = v + rv[q];
  }
  *(f32x4*)(out + (size_t)node*DHC + c4) = o;
}

extern "C" void kernel_launch(void* const* d_in, const int* in_sizes, int n_in,
                              void* d_out, int out_size, void* d_ws, size_t ws_size,
                              hipStream_t stream){
  (void)in_sizes; (void)n_in; (void)out_size; (void)ws_size;
  const float* x     = (const float*)d_in[0];
  const int*   ei    = (const int*)d_in[1];
  const float* ln_g  = (const float*)d_in[2];
  const float* ln_b  = (const float*)d_in[3];
  const float* W1    = (const float*)d_in[4];
  const float* b1    = (const float*)d_in[5];
  const float* W2    = (const float*)d_in[6];
  const float* b2    = (const float*)d_in[7];
  const float* Wr    = (const float*)d_in[8];
  const float* br    = (const float*)d_in[9];
  const float* Wg    = (const float*)d_in[10];
  const float* att_s = (const float*)d_in[11];
  const float* att_d = (const float*)d_in[12];
  const float* bg    = (const float*)d_in[13];
  float* out = (float*)d_out;

  char* p = (char*)d_ws;
  ushort_t* xn   = (ushort_t*)(p);                   // [0, 153,600,000)
  ushort_t* h1   = (ushort_t*)(p + 153600000);       // -> 256,000,000
  float*    asrc = (float*)(p + 256000000);
  float*    adst = (float*)(p + 257600000);
  int*      cnt  = (int*)(p + 259200000);
  int*      offs = (int*)(p + 259400064);
  int*      cur  = (int*)(p + 259600128);
  int*      eidx = (int*)(p + 259800192);            // -> 263,200,192
  ushort_t* W1T  = (ushort_t*)d_out;                           // 3,145,728
  ushort_t* WrgT = (ushort_t*)((char*)d_out + 3145728);        //   524,288
  ushort_t* W2bf = (ushort_t*)((char*)d_out + 3670016);        // 1,048,576
  ushort_t* WcT  = (ushort_t*)((char*)d_out + 4718592);        // 1,048,576
  float*    b2rg = (float*)((char*)d_out + 5767168);           //     2,048
  float*    res  = (float*)(p + 0);                  //  51,200,000 (f32)
  ushort_t* gm   = (ushort_t*)(p + 51200000);        //  25,600,000 (bf16)

  // k0: zero edge counters (DMA)
  hipMemsetAsync(cnt, 0, NND*sizeof(int), stream);

  // k1: fused count_edges(x4) + LN (1-pass, 16B stores) + weight prep
  fused1<<<F1_LN + 2050, 256, 0, stream>>>(
      x, ln_g, ln_b, xn, ei, cnt,
      W1, Wr, Wg, W2, b2, br, W1T, WrgT, W2bf, b2rg);

  // k2: GEMM1 8-phase (blk 0-783) + scan (784) + WcT tiny GEMM (785-792)
  mega_gemm<<<G1_NWG + 9, 512, 0, stream>>>(xn, W1T, b1, h1, WrgT, W2bf, WcT,
                                            cnt, offs, cur);

  // k3: 8-phase fused [res|gm] = h1 @ WcT^T + b2rg (split + att + fill)
  gemm3p8<<<G3_NWG + (NND + NE + 511)/512, 512, 0, stream>>>(
      h1, WcT, b2rg, res, gm,
      ei, cur, eidx, att_s, att_d, asrc, adst);

  // k4: GAT aggregate
  gat_agg<<<(NND + 3)/4, 256, 0, stream>>>(offs, eidx, asrc, adst, gm, res, bg, out);
}

// Round 18
// 482.747 us; speedup vs baseline: 1.0279x; 1.0279x over previous
//
#include <hip/hip_runtime.h>
#include <hip/hip_bf16.h>
#include <cstdint>
#include <cstddef>

#define NND 50000
#define DIN 1488
#define DINP 1536
#define DHID 1024
#define DOUT 512
#define DHC 256
#define NE 800000
#define NHD 8

typedef __attribute__((ext_vector_type(8))) short short8;
typedef __attribute__((ext_vector_type(4))) short short4v;
typedef __attribute__((ext_vector_type(4))) float f32x4;
typedef __attribute__((ext_vector_type(4))) int int4v;
typedef unsigned short ushort_t;

__device__ __forceinline__ unsigned short f2bf(float f){
  union { float f; unsigned u; } v; v.f = f;
  unsigned r = v.u + 0x7fffu + ((v.u >> 16) & 1u);
  return (unsigned short)(r >> 16);
}
__device__ __forceinline__ float bf2f(unsigned short u){
  union { unsigned u; float f; } v; v.u = ((unsigned)u) << 16;
  return v.f;
}

__device__ __forceinline__ void async16(const void* g, void* l){
  __builtin_amdgcn_global_load_lds((__attribute__((address_space(1))) void*)g,
                                   (__attribute__((address_space(3))) void*)l, 16, 0, 0);
}

// ---- fused stage 1: count_edges(x4) + LN (1-pass, 16B stores) + prep -------
__device__ __forceinline__ void tc_tile(const float* __restrict__ W,
                                        ushort_t* __restrict__ WT,
                                        int K, int Nn, int Kp, int bx, int by){
  __shared__ float tile[32][33];
  const int tx = threadIdx.x & 31, ty = threadIdx.x >> 5;
  const int k0 = bx*32, n0 = by*32;
  for (int i = ty; i < 32; i += 8){
    int k = k0 + i, n = n0 + tx;
    tile[i][tx] = (k < K && n < Nn) ? W[(size_t)k*Nn + n] : 0.f;
  }
  __syncthreads();
  for (int i = ty; i < 32; i += 8){
    int n = n0 + i, k = k0 + tx;
    if (n < Nn && k < Kp) WT[(size_t)n*Kp + k] = f2bf(tile[tx][i]);
  }
}

#define F1_CNT  782
#define F1_LN   (F1_CNT + 12500)
__global__ __launch_bounds__(256) void fused1(const float* __restrict__ x,
                                              const float* __restrict__ gw,
                                              const float* __restrict__ bw,
                                              ushort_t* __restrict__ xn,
                                              const int* __restrict__ ei,
                                              int* __restrict__ cnt,
                                              const float* W1, const float* Wr,
                                              const float* Wg, const float* W2,
                                              const float* b2, const float* br,
                                              ushort_t* W1T, ushort_t* WrgT,
                                              ushort_t* W2bf, float* b2rg){
  const int bid = blockIdx.x;
  if (bid < F1_CNT){
    int i4 = bid*256 + threadIdx.x;
    if (i4 < NE/4){
      int4v v = *(const int4v*)(ei + NE + i4*4);
      atomicAdd(&cnt[v.x], 1); atomicAdd(&cnt[v.y], 1);
      atomicAdd(&cnt[v.z], 1); atomicAdd(&cnt[v.w], 1);
    }
    return;
  }
  if (bid < F1_LN){
    const int wid = threadIdx.x >> 6, lane = threadIdx.x & 63;
    const int row = (bid - F1_CNT)*4 + wid;
    if (row >= NND) return;
    const float* xr = x + (size_t)row * DIN;
    f32x4 xa[3], xb[3];
    float s = 0.f, sq = 0.f;
    #pragma unroll
    for (int it = 0; it < 3; ++it){
      const int i = lane*8 + it*512;
      if (i < DIN){
        xa[it] = *(const f32x4*)(xr + i);
        xb[it] = *(const f32x4*)(xr + i + 4);
      } else {
        xa[it] = (f32x4){0.f,0.f,0.f,0.f};
        xb[it] = (f32x4){0.f,0.f,0.f,0.f};
      }
      s  += xa[it].x + xa[it].y + xa[it].z + xa[it].w
          + xb[it].x + xb[it].y + xb[it].z + xb[it].w;
      sq += xa[it].x*xa[it].x + xa[it].y*xa[it].y + xa[it].z*xa[it].z + xa[it].w*xa[it].w
          + xb[it].x*xb[it].x + xb[it].y*xb[it].y + xb[it].z*xb[it].z + xb[it].w*xb[it].w;
    }
    #pragma unroll
    for (int o = 32; o; o >>= 1){ s += __shfl_xor(s, o); sq += __shfl_xor(sq, o); }
    const float mu = s * (1.f/DIN);
    const float var = sq * (1.f/DIN) - mu*mu;
    const float rstd = rsqrtf(var + 1e-5f);
    ushort_t* xo = xn + (size_t)row * DINP;
    #pragma unroll
    for (int it = 0; it < 3; ++it){
      const int i = lane*8 + it*512;
      union { ushort_t u[8]; short8 v; } o;
      if (i < DIN){
        f32x4 ga = *(const f32x4*)(gw + i);
        f32x4 gb = *(const f32x4*)(gw + i + 4);
        f32x4 ba = *(const f32x4*)(bw + i);
        f32x4 bb = *(const f32x4*)(bw + i + 4);
        o.u[0] = f2bf((xa[it].x-mu)*rstd*ga.x + ba.x);
        o.u[1] = f2bf((xa[it].y-mu)*rstd*ga.y + ba.y);
        o.u[2] = f2bf((xa[it].z-mu)*rstd*ga.z + ba.z);
        o.u[3] = f2bf((xa[it].w-mu)*rstd*ga.w + ba.w);
        o.u[4] = f2bf((xb[it].x-mu)*rstd*gb.x + bb.x);
        o.u[5] = f2bf((xb[it].y-mu)*rstd*gb.y + bb.y);
        o.u[6] = f2bf((xb[it].z-mu)*rstd*gb.z + bb.z);
        o.u[7] = f2bf((xb[it].w-mu)*rstd*gb.w + bb.w);
      } else {
        o.u[0]=o.u[1]=o.u[2]=o.u[3]=o.u[4]=o.u[5]=o.u[6]=o.u[7]=0;
      }
      *(short8*)(xo + i) = o.v;
    }
    return;
  }
  {
    int b = bid - F1_LN;
    if (b < 1536){ tc_tile(W1, W1T, DIN, DHID, DINP, b % 48, b / 48); return; }
    b -= 1536;
    if (b < 128){ tc_tile(Wr, WrgT, DOUT, DHC, DOUT, b % 16, b / 16); return; }
    b -= 128;
    if (b < 128){ tc_tile(Wg, WrgT + 256*DOUT, DOUT, DHC, DOUT, b % 16, b / 16); return; }
    b -= 128;
    if (b < 256){
      const int idx = (b*256 + threadIdx.x)*8;
      f32x4 v0 = *(const f32x4*)(W2 + idx);
      f32x4 v1 = *(const f32x4*)(W2 + idx + 4);
      union { ushort_t u[8]; short8 s; } o;
      o.u[0]=f2bf(v0.x); o.u[1]=f2bf(v0.y); o.u[2]=f2bf(v0.z); o.u[3]=f2bf(v0.w);
      o.u[4]=f2bf(v1.x); o.u[5]=f2bf(v1.y); o.u[6]=f2bf(v1.z); o.u[7]=f2bf(v1.w);
      *(short8*)(W2bf + idx) = o.s;
      return;
    }
    b -= 256;
    {
      const int c = b*256 + threadIdx.x;
      float acc = 0.f;
      if (c < 256){
        for (int j = 0; j < DOUT; ++j) acc += b2[j]*Wr[(size_t)j*DHC + c];
        acc += br[c];
      } else {
        const int cc = c - 256;
        for (int j = 0; j < DOUT; ++j) acc += b2[j]*Wg[(size_t)j*DHC + cc];
      }
      b2rg[c] = acc;
      return;
    }
  }
}

// ------- 256x256 8-phase GEMM body (device fn; runtime act; bf16 out) -------
__device__ __forceinline__ void g256p8_body(ushort_t (&lds)[2][2][2][64*128],
                                            const ushort_t* __restrict__ A,
                                            const ushort_t* __restrict__ BT,
                                            const float* __restrict__ bias,
                                            ushort_t* __restrict__ out0,
                                            int M, int Nn, int K,
                                            int bid, int nwg, bool act){
  const int t = threadIdx.x, wid = t >> 6, lane = t & 63;
  const int CB = Nn >> 8;
  const int q = nwg >> 3, r = nwg & 7;
  const int xcd = bid & 7, slot = bid >> 3;
  const int lg = (xcd < r ? xcd*(q+1) : r*(q+1) + (xcd - r)*q) + slot;
  const int brow = (lg / CB) * 256, bcol = (lg % CB) * 256;

  const int l8  = t >> 3;
  const int cb  = (t & 7) << 4;
  const unsigned scb = (unsigned)(cb ^ ((l8 & 7) << 4));
  unsigned rowA[2][2], rowB[2][2];
  #pragma unroll
  for (int hf = 0; hf < 2; ++hf)
    #pragma unroll
    for (int rd = 0; rd < 2; ++rd){
      int ra = brow + hf*128 + rd*64 + l8; ra = ra < M ? ra : M-1;
      int rb = bcol + hf*128 + rd*64 + l8; rb = rb < Nn ? rb : Nn-1;
      rowA[hf][rd] = (unsigned)ra * (unsigned)(K*2);
      rowB[hf][rd] = (unsigned)rb * (unsigned)(K*2);
    }
  const int w8 = wid * 8;

#define STG_A(buf, hf, kt) do {                                               \
    const unsigned _ob = (unsigned)(kt)*128u + scb;                           \
    async16((const char*)A + rowA[hf][0] + _ob, &lds[buf][0][hf][(w8)*64]);   \
    async16((const char*)A + rowA[hf][1] + _ob, &lds[buf][0][hf][(64+w8)*64]);\
  } while(0)
#define STG_B(buf, hf, kt) do {                                               \
    const unsigned _ob = (unsigned)(kt)*128u + scb;                           \
    async16((const char*)BT + rowB[hf][0] + _ob, &lds[buf][1][hf][(w8)*64]);  \
    async16((const char*)BT + rowB[hf][1] + _ob, &lds[buf][1][hf][(64+w8)*64]);\
  } while(0)

  f32x4 acc[8][4];
  #pragma unroll
  for (int i=0;i<8;i++)
    #pragma unroll
    for (int j=0;j<4;j++) acc[i][j] = (f32x4){0.f,0.f,0.f,0.f};

  const int wrow = (wid >> 2), wcol = (wid & 3);
  const int fr = lane & 15;
  const int kb0 = (lane >> 4) << 4;
  const int sx  = (fr & 7) << 4;
  const int ko0 = ((kb0      ) ^ sx) >> 1;
  const int ko1 = ((kb0 | 64 ) ^ sx) >> 1;
  const int bhalf = wcol >> 1, brl = (wcol & 1)*64;

#define RD_A(buf, m) do {                                          \
    const int _ra = ((m)*16 + fr)*64;                              \
    af[m][0] = *(const short8*)&lds[buf][0][wrow][_ra + ko0];      \
    af[m][1] = *(const short8*)&lds[buf][0][wrow][_ra + ko1];      \
  } while(0)
#define RD_B(buf, n) do {                                          \
    const int _rb = (brl + (n)*16 + fr)*64;                        \
    bf[n][0] = *(const short8*)&lds[buf][1][bhalf][_rb + ko0];     \
    bf[n][1] = *(const short8*)&lds[buf][1][bhalf][_rb + ko1];     \
  } while(0)
#define SYNC_PH() do {                                             \
    __builtin_amdgcn_s_barrier();                                  \
    asm volatile("s_waitcnt lgkmcnt(0)" ::: "memory");             \
    __builtin_amdgcn_sched_barrier(0);                             \
  } while(0)
#define MFMA_Q(M0, N0) do {                                        \
    __builtin_amdgcn_s_setprio(1);                                 \
    _Pragma("unroll")                                              \
    for (int _m=(M0); _m<(M0)+4; ++_m)                             \
      _Pragma("unroll")                                            \
      for (int _n=(N0); _n<(N0)+2; ++_n){                          \
        acc[_m][_n] = __builtin_amdgcn_mfma_f32_16x16x32_bf16(af[_m][0], bf[_n][0], acc[_m][_n], 0, 0, 0); \
        acc[_m][_n] = __builtin_amdgcn_mfma_f32_16x16x32_bf16(af[_m][1], bf[_n][1], acc[_m][_n], 0, 0, 0); \
      }                                                            \
    __builtin_amdgcn_s_setprio(0);                                 \
  } while(0)

  const int nk = K >> 6;
  STG_A(0,0,0); STG_A(0,1,0); STG_B(0,0,0); STG_B(0,1,0);
  STG_A(1,0,1); STG_A(1,1,1);
  asm volatile("s_waitcnt vmcnt(4)" ::: "memory");
  __builtin_amdgcn_s_barrier();

  for (int kt = 0; kt < nk; ++kt){
    const int buf = kt & 1, obuf = buf ^ 1;
    short8 af[8][2], bf[4][2];
    RD_A(buf,0); RD_A(buf,1); RD_A(buf,2); RD_A(buf,3);
    RD_B(buf,0); RD_B(buf,1);
    if (kt + 1 < nk) STG_B(obuf, 0, kt + 1);
    SYNC_PH();
    MFMA_Q(0, 0);
    RD_A(buf,4); RD_A(buf,5); RD_A(buf,6); RD_A(buf,7);
    if (kt + 1 < nk) STG_B(obuf, 1, kt + 1);
    SYNC_PH();
    MFMA_Q(4, 0);
    RD_B(buf,2); RD_B(buf,3);
    if (kt + 2 < nk) STG_A(buf, 0, kt + 2);
    SYNC_PH();
    MFMA_Q(0, 2);
    if (kt + 2 < nk){
      STG_A(buf, 1, kt + 2);
      asm volatile("s_waitcnt vmcnt(4)" ::: "memory");
    } else {
      asm volatile("s_waitcnt vmcnt(0)" ::: "memory");
    }
    __builtin_amdgcn_s_barrier();
    MFMA_Q(4, 2);
  }
#undef STG_A
#undef STG_B
#undef RD_A
#undef RD_B
#undef SYNC_PH
#undef MFMA_Q

  float bv[4];
  #pragma unroll
  for (int n=0;n<4;n++){
    const int col = bcol + wcol*64 + n*16 + (lane & 15);
    bv[n] = bias ? bias[col] : 0.f;
  }
  ushort_t* sB = (ushort_t*)&lds[0][0][0][0];
  __syncthreads();
  #pragma unroll
  for (int m=0;m<8;m++){
    const int row = wrow*128 + m*16 + (lane >> 4)*4;
    #pragma unroll
    for (int n=0;n<4;n++){
      const int col = wcol*64 + n*16 + (lane & 15);
      #pragma unroll
      for (int j=0;j<4;j++){
        float v = acc[m][n][j] + bv[n];
        if (act) v = v > 0.f ? v : 0.f;
        sB[(row+j)*256 + col] = f2bf(v);
      }
    }
  }
  __syncthreads();
  const int srow = t >> 5, scol8 = (t & 31) * 8;
  #pragma unroll
  for (int rr = 0; rr < 16; ++rr){
    const int rloc = rr*16 + srow;
    const int grow = brow + rloc;
    if (grow < M)
      *(short8*)(out0 + (size_t)grow*Nn + bcol + scol8) = *(const short8*)&sB[rloc*256 + scol8];
  }
}

// ---- k2 mega kernel: scan (blk 0) + WcT tiny GEMM (blk 1-8) + GEMM1 --------
__global__ __launch_bounds__(512, 1) void mega_gemm(const ushort_t* __restrict__ xn,
                                                    const ushort_t* __restrict__ W1T,
                                                    const float* __restrict__ b1,
                                                    ushort_t* __restrict__ h1,
                                                    const ushort_t* __restrict__ WrgT,
                                                    const ushort_t* __restrict__ W2bf,
                                                    ushort_t* __restrict__ WcT,
                                                    const int* __restrict__ cnt,
                                                    int* __restrict__ offs,
                                                    int* __restrict__ cur){
  __shared__ __align__(16) ushort_t lds[2][2][2][64*128];  // 128 KiB
  const int t = threadIdx.x;

  if (blockIdx.x == 0){
    int* sbuf = (int*)&lds[0][0][0][0];
    const int chunk = (NND + 255) >> 8;                  // 196, mult of 4
    int s = 0;
    if (t < 256){
      const int s0 = t*chunk;
      const int s1 = (s0 + chunk < NND) ? s0 + chunk : NND;
      for (int i = s0; i < s1; i += 4){
        int4v v = *(const int4v*)(cnt + i);
        s += v.x + v.y + v.z + v.w + 4;
      }
    }
    sbuf[t] = s; __syncthreads();
    for (int o = 1; o < 256; o <<= 1){
      int xv = (t >= o && t < 256) ? sbuf[t-o] : 0;
      __syncthreads();
      if (t < 256) sbuf[t] += xv;
      __syncthreads();
    }
    if (t < 256){
      int run = sbuf[t] - s;
      const int s0 = t*chunk;
      const int s1 = (s0 + chunk < NND) ? s0 + chunk : NND;
      for (int i = s0; i < s1; i += 4){
        int4v v = *(const int4v*)(cnt + i);
        int4v cu;
        cu.x = run; run += v.x + 1;
        cu.y = run; run += v.y + 1;
        cu.z = run; run += v.z + 1;
        cu.w = run; run += v.w + 1;
        *(int4v*)(cur + i)  = cu;
        *(int4v*)(offs + i) = cu;
      }
      if (t == 255) offs[NND] = run;
    }
    return;
  }
  if (blockIdx.x < 9){
    g256p8_body(lds, WrgT, W2bf, nullptr, WcT, 512, 1024, 512,
                (int)blockIdx.x - 1, 8, false);
    return;
  }
  g256p8_body(lds, xn, W1T, b1, h1, NND, DHID, DINP,
              (int)blockIdx.x - 9, (int)gridDim.x - 9, true);
}

// ---- k3: 8-phase GEMM [res|gm] = h1 @ WcT^T + b2rg, split epilogue + att ---
#define G3_NWG 392
__global__ __launch_bounds__(512, 1) void gemm3p8(const ushort_t* __restrict__ A,
                                                  const ushort_t* __restrict__ BT,
                                                  const float* __restrict__ bias,
                                                  float* __restrict__ res,
                                                  ushort_t* __restrict__ gm,
                                                  const int* __restrict__ ei,
                                                  int* __restrict__ cur,
                                                  int* __restrict__ eidx,
                                                  const float* __restrict__ att_s,
                                                  const float* __restrict__ att_d,
                                                  float* __restrict__ asrc,
                                                  float* __restrict__ adst){
  __shared__ __align__(16) ushort_t lds[2][2][2][64*128];  // 128 KiB
  const int t = threadIdx.x, wid = t >> 6, lane = t & 63;

  if (blockIdx.x >= G3_NWG){
    int i = (blockIdx.x - G3_NWG)*512 + t;
    if (i < NND){
      int p = atomicAdd(&cur[i], 1); eidx[p] = i;
    } else if (i < NND + NE){
      int e = i - NND;
      int src = ei[e], dst = ei[NE + e];
      int p = atomicAdd(&cur[dst], 1);
      eidx[p] = src;
    }
    return;
  }

  const int M = NND, Nn = 512, K = DHID;
  const int bid = blockIdx.x, nwg = G3_NWG;
  const int CB = 2;
  const int q = nwg >> 3, r = nwg & 7;
  const int xcd = bid & 7, slot = bid >> 3;
  const int lg = (xcd < r ? xcd*(q+1) : r*(q+1) + (xcd - r)*q) + slot;
  const int brow = (lg / CB) * 256, bcol = (lg % CB) * 256;

  const int l8  = t >> 3;
  const int cb  = (t & 7) << 4;
  const unsigned scb = (unsigned)(cb ^ ((l8 & 7) << 4));
  unsigned rowA[2][2], rowB[2][2];
  #pragma unroll
  for (int hf = 0; hf < 2; ++hf)
    #pragma unroll
    for (int rd = 0; rd < 2; ++rd){
      int ra = brow + hf*128 + rd*64 + l8; ra = ra < M ? ra : M-1;
      int rb = bcol + hf*128 + rd*64 + l8; rb = rb < Nn ? rb : Nn-1;
      rowA[hf][rd] = (unsigned)ra * (unsigned)(K*2);
      rowB[hf][rd] = (unsigned)rb * (unsigned)(K*2);
    }
  const int w8 = wid * 8;

#define STG_A(buf, hf, kt) do {                                               \
    const unsigned _ob = (unsigned)(kt)*128u + scb;                           \
    async16((const char*)A + rowA[hf][0] + _ob, &lds[buf][0][hf][(w8)*64]);   \
    async16((const char*)A + rowA[hf][1] + _ob, &lds[buf][0][hf][(64+w8)*64]);\
  } while(0)
#define STG_B(buf, hf, kt) do {                                               \
    const unsigned _ob = (unsigned)(kt)*128u + scb;                           \
    async16((const char*)BT + rowB[hf][0] + _ob, &lds[buf][1][hf][(w8)*64]);  \
    async16((const char*)BT + rowB[hf][1] + _ob, &lds[buf][1][hf][(64+w8)*64]);\
  } while(0)

  f32x4 acc[8][4];
  #pragma unroll
  for (int i=0;i<8;i++)
    #pragma unroll
    for (int j=0;j<4;j++) acc[i][j] = (f32x4){0.f,0.f,0.f,0.f};

  const int wrow = (wid >> 2), wcol = (wid & 3);
  const int fr = lane & 15;
  const int kb0 = (lane >> 4) << 4;
  const int sx  = (fr & 7) << 4;
  const int ko0 = ((kb0      ) ^ sx) >> 1;
  const int ko1 = ((kb0 | 64 ) ^ sx) >> 1;
  const int bhalf = wcol >> 1, brl = (wcol & 1)*64;

#define RD_A(buf, m) do {                                          \
    const int _ra = ((m)*16 + fr)*64;                              \
    af[m][0] = *(const short8*)&lds[buf][0][wrow][_ra + ko0];      \
    af[m][1] = *(const short8*)&lds[buf][0][wrow][_ra + ko1];      \
  } while(0)
#define RD_B(buf, n) do {                                          \
    const int _rb = (brl + (n)*16 + fr)*64;                        \
    bf[n][0] = *(const short8*)&lds[buf][1][bhalf][_rb + ko0];     \
    bf[n][1] = *(const short8*)&lds[buf][1][bhalf][_rb + ko1];     \
  } while(0)
#define SYNC_PH() do {                                             \
    __builtin_amdgcn_s_barrier();                                  \
    asm volatile("s_waitcnt lgkmcnt(0)" ::: "memory");             \
    __builtin_amdgcn_sched_barrier(0);                             \
  } while(0)
#define MFMA_Q(M0, N0) do {                                        \
    __builtin_amdgcn_s_setprio(1);                                 \
    _Pragma("unroll")                                              \
    for (int _m=(M0); _m<(M0)+4; ++_m)                             \
      _Pragma("unroll")                                            \
      for (int _n=(N0); _n<(N0)+2; ++_n){                          \
        acc[_m][_n] = __builtin_amdgcn_mfma_f32_16x16x32_bf16(af[_m][0], bf[_n][0], acc[_m][_n], 0, 0, 0); \
        acc[_m][_n] = __builtin_amdgcn_mfma_f32_16x16x32_bf16(af[_m][1], bf[_n][1], acc[_m][_n], 0, 0, 0); \
      }                                                            \
    __builtin_amdgcn_s_setprio(0);                                 \
  } while(0)

  const int nk = K >> 6;
  STG_A(0,0,0); STG_A(0,1,0); STG_B(0,0,0); STG_B(0,1,0);
  STG_A(1,0,1); STG_A(1,1,1);
  asm volatile("s_waitcnt vmcnt(4)" ::: "memory");
  __builtin_amdgcn_s_barrier();

  for (int kt = 0; kt < nk; ++kt){
    const int buf = kt & 1, obuf = buf ^ 1;
    short8 af[8][2], bf[4][2];
    RD_A(buf,0); RD_A(buf,1); RD_A(buf,2); RD_A(buf,3);
    RD_B(buf,0); RD_B(buf,1);
    if (kt + 1 < nk) STG_B(obuf, 0, kt + 1);
    SYNC_PH();
    MFMA_Q(0, 0);
    RD_A(buf,4); RD_A(buf,5); RD_A(buf,6); RD_A(buf,7);
    if (kt + 1 < nk) STG_B(obuf, 1, kt + 1);
    SYNC_PH();
    MFMA_Q(4, 0);
    RD_B(buf,2); RD_B(buf,3);
    if (kt + 2 < nk) STG_A(buf, 0, kt + 2);
    SYNC_PH();
    MFMA_Q(0, 2);
    if (kt + 2 < nk){
      STG_A(buf, 1, kt + 2);
      asm volatile("s_waitcnt vmcnt(4)" ::: "memory");
    } else {
      asm volatile("s_waitcnt vmcnt(0)" ::: "memory");
    }
    __builtin_amdgcn_s_barrier();
    MFMA_Q(4, 2);
  }
#undef STG_A
#undef STG_B
#undef RD_A
#undef RD_B
#undef SYNC_PH
#undef MFMA_Q

  float bv[4];
  #pragma unroll
  for (int n=0;n<4;n++){
    const int col = bcol + wcol*64 + n*16 + (lane & 15);
    bv[n] = bias[col];
  }
  if (bcol == 0){
    float* sF = (float*)&lds[0][0][0][0];            // [128][256] f32
    #pragma unroll
    for (int p = 0; p < 2; ++p){
      __syncthreads();
      if (wrow == p){
        #pragma unroll
        for (int m=0;m<8;m++){
          const int row = m*16 + (lane >> 4)*4;
          #pragma unroll
          for (int n=0;n<4;n++){
            const int col = wcol*64 + n*16 + (lane & 15);
            #pragma unroll
            for (int j=0;j<4;j++)
              sF[(row+j)*256 + col] = acc[m][n][j] + bv[n];
          }
        }
      }
      __syncthreads();
      const int srow = t >> 6, scol4 = (t & 63) * 4;
      #pragma unroll
      for (int rr = 0; rr < 16; ++rr){
        const int rloc = rr*8 + srow;
        const int grow = brow + p*128 + rloc;
        if (grow < M)
          *(f32x4*)(res + (size_t)grow*256 + scol4) = *(const f32x4*)&sF[rloc*256 + scol4];
      }
    }
  } else {
    ushort_t* sB = (ushort_t*)&lds[0][0][0][0];      // [256][256] bf16
    __syncthreads();
    #pragma unroll
    for (int m=0;m<8;m++){
      const int row = wrow*128 + m*16 + (lane >> 4)*4;
      #pragma unroll
      for (int n=0;n<4;n++){
        const int col = wcol*64 + n*16 + (lane & 15);
        #pragma unroll
        for (int j=0;j<4;j++)
          sB[(row+j)*256 + col] = f2bf(acc[m][n][j] + bv[n]);
      }
    }
    __syncthreads();
    const int srow = t >> 5, scol8 = (t & 31) * 8;
    #pragma unroll
    for (int rr = 0; rr < 16; ++rr){
      const int rloc = rr*16 + srow;
      const int grow = brow + rloc;
      if (grow < M)
        *(short8*)(gm + (size_t)grow*256 + scol8) = *(const short8*)&sB[rloc*256 + scol8];
    }
    const int h = t & 7;
    const int hc0 = h * 32;
    #pragma unroll
    for (int k = 0; k < 4; ++k){
      const int rloc = (t >> 3) + k*64;
      const int grow = brow + rloc;
      if (grow < M){
        float a = 0.f, d = 0.f;
        #pragma unroll
        for (int c0 = 0; c0 < 32; c0 += 8){
          short8 gv = *(const short8*)&sB[rloc*256 + hc0 + c0];
          #pragma unroll
          for (int j = 0; j < 8; ++j){
            float g = bf2f((ushort_t)gv[j]);
            a += g*att_s[hc0 + c0 + j];
            d += g*att_d[hc0 + c0 + j];
          }
        }
        asrc[grow*NHD + h] = a;
        adst[grow*NHD + h] = d;
      }
    }
  }
}

// ---- fused GAT aggregate (wave/node, 8-edge chunks, 2-deep pipeline) ------
__global__ __launch_bounds__(256) void gat_agg(const int* __restrict__ offs,
                                               const int* __restrict__ eidx,
                                               const float* __restrict__ asrc,
                                               const float* __restrict__ adst,
                                               const ushort_t* __restrict__ gm,
                                               const float* __restrict__ res,
                                               const float* __restrict__ bg,
                                               float* __restrict__ out){
  const int wid = threadIdx.x >> 6, lane = threadIdx.x & 63;
  const int node = blockIdx.x*4 + wid;
  if (node >= NND) return;
  const int h = lane >> 3, jj = lane & 7;
  const int e0 = offs[node], deg = offs[node+1] - e0;
  const float adv = adst[node*NHD + h];

  float mx = -1e30f;
  for (int j = jj; j < deg; j += 8){
    int s = eidx[e0 + j];
    float e = asrc[s*NHD + h] + adv; e = e > 0.f ? e : 0.2f*e;
    mx = fmaxf(mx, e);
  }
  mx = fmaxf(mx, __shfl_xor(mx, 1));
  mx = fmaxf(mx, __shfl_xor(mx, 2));
  mx = fmaxf(mx, __shfl_xor(mx, 4));

  const int c4 = lane*4;
  float sm = 0.f;
  f32x4 acc = {0.f,0.f,0.f,0.f};

  int s = 0; float w = 0.f;
  {
    const int cnt0 = deg < 8 ? deg : 8;
    if (jj < cnt0){
      s = eidx[e0 + jj];
      float e = asrc[s*NHD + h] + adv; e = e > 0.f ? e : 0.2f*e;
      w = __expf(e - mx);
      sm += w;
    }
  }
  for (int j0 = 0; j0 < deg; j0 += 8){
    const int cnt = (deg - j0) < 8 ? (deg - j0) : 8;
    int ns = 0; float nw = 0.f;
    const int ncnt = (deg - j0 - 8) < 8 ? (deg - j0 - 8) : 8;
    if (jj < ncnt){
      ns = eidx[e0 + j0 + 8 + jj];
      float e = asrc[ns*NHD + h] + adv; e = e > 0.f ? e : 0.2f*e;
      nw = __expf(e - mx);
      sm += nw;
    }
    #pragma unroll
    for (int u = 0; u < 8; ++u){
      if (u < cnt){
        const int   su = __builtin_amdgcn_readlane(s, u);
        const float wu = __shfl(w, (h << 3) | u);
        short4v gv = *(const short4v*)(gm + (size_t)su*DHC + c4);
        acc.x += wu*bf2f((ushort_t)gv.x);
        acc.y += wu*bf2f((ushort_t)gv.y);
        acc.z += wu*bf2f((ushort_t)gv.z);
        acc.w += wu*bf2f((ushort_t)gv.w);
      }
    }
    s = ns; w = nw;
  }
  sm += __shfl_xor(sm, 1); sm += __shfl_xor(sm, 2); sm += __shfl_xor(sm, 4);
  const float inv = 1.f/(sm + 1e-16f);

  f32x4 bgv = *(const f32x4*)(bg + c4);
  f32x4 rv  = *(const f32x4*)(res + (size_t)node*DHC + c4);
  f32x4 o;
  #pragma unroll
  for (int q = 0; q < 4; ++q){
    float v = acc[q]*inv + bgv[q];
    v = v > 0.f ? v : expm1f(v);
    o[q] = v + rv[q];
  }
  *(f32x4*)(out + (size_t)node*DHC + c4) = o;
}

extern "C" void kernel_launch(void* const* d_in, const int* in_sizes, int n_in,
                              void* d_out, int out_size, void* d_ws, size_t ws_size,
                              hipStream_t stream){
  (void)in_sizes; (void)n_in; (void)out_size; (void)ws_size;
  const float* x     = (const float*)d_in[0];
  const int*   ei    = (const int*)d_in[1];
  const float* ln_g  = (const float*)d_in[2];
  const float* ln_b  = (const float*)d_in[3];
  const float* W1    = (const float*)d_in[4];
  const float* b1    = (const float*)d_in[5];
  const float* W2    = (const float*)d_in[6];
  const float* b2    = (const float*)d_in[7];
  const float* Wr    = (const float*)d_in[8];
  const float* br    = (const float*)d_in[9];
  const float* Wg    = (const float*)d_in[10];
  const float* att_s = (const float*)d_in[11];
  const float* att_d = (const float*)d_in[12];
  const float* bg    = (const float*)d_in[13];
  float* out = (float*)d_out;

  char* p = (char*)d_ws;
  ushort_t* xn   = (ushort_t*)(p);                   // [0, 153,600,000)
  ushort_t* h1   = (ushort_t*)(p + 153600000);       // -> 256,000,000
  float*    asrc = (float*)(p + 256000000);
  float*    adst = (float*)(p + 257600000);
  int*      cnt  = (int*)(p + 259200000);
  int*      offs = (int*)(p + 259400064);
  int*      cur  = (int*)(p + 259600128);
  int*      eidx = (int*)(p + 259800192);            // -> 263,200,192
  ushort_t* W1T  = (ushort_t*)d_out;                           // 3,145,728
  ushort_t* WrgT = (ushort_t*)((char*)d_out + 3145728);        //   524,288
  ushort_t* W2bf = (ushort_t*)((char*)d_out + 3670016);        // 1,048,576
  ushort_t* WcT  = (ushort_t*)((char*)d_out + 4718592);        // 1,048,576
  float*    b2rg = (float*)((char*)d_out + 5767168);           //     2,048
  float*    res  = (float*)(p + 0);                  //  51,200,000 (f32)
  ushort_t* gm   = (ushort_t*)(p + 51200000);        //  25,600,000 (bf16)

  // k0: zero edge counters (DMA)
  hipMemsetAsync(cnt, 0, NND*sizeof(int), stream);

  // k1: fused count_edges(x4) + LN (1-pass, 16B stores) + weight prep
  fused1<<<F1_LN + 2050, 256, 0, stream>>>(
      x, ln_g, ln_b, xn, ei, cnt,
      W1, Wr, Wg, W2, b2, br, W1T, WrgT, W2bf, b2rg);

  // k2: scan (blk 0) + WcT tiny GEMM (blk 1-8) + GEMM1 8-phase (784 blks)
  mega_gemm<<<793, 512, 0, stream>>>(xn, W1T, b1, h1, WrgT, W2bf, WcT,
                                     cnt, offs, cur);

  // k3: 8-phase fused [res|gm] = h1 @ WcT^T + b2rg (split + att + fill)
  gemm3p8<<<G3_NWG + (NND + NE + 511)/512, 512, 0, stream>>>(
      h1, WcT, b2rg, res, gm,
      ei, cur, eidx, att_s, att_d, asrc, adst);

  // k4: GAT aggregate
  gat_agg<<<(NND + 3)/4, 256, 0, stream>>>(offs, eidx, asrc, adst, gm, res, bg, out);
}

// Round 19
// 477.029 us; speedup vs baseline: 1.0402x; 1.0120x over previous
//
#include <hip/hip_runtime.h>
#include <hip/hip_bf16.h>
#include <cstdint>
#include <cstddef>

#define NND 50000
#define DIN 1488
#define DINP 1536
#define DHID 1024
#define DOUT 512
#define DHC 256
#define NE 800000
#define NHD 8

typedef __attribute__((ext_vector_type(8))) short short8;
typedef __attribute__((ext_vector_type(4))) short short4v;
typedef __attribute__((ext_vector_type(4))) float f32x4;
typedef __attribute__((ext_vector_type(4))) int int4v;
typedef unsigned short ushort_t;

__device__ __forceinline__ unsigned short f2bf(float f){
  union { float f; unsigned u; } v; v.f = f;
  unsigned r = v.u + 0x7fffu + ((v.u >> 16) & 1u);
  return (unsigned short)(r >> 16);
}
__device__ __forceinline__ float bf2f(unsigned short u){
  union { unsigned u; float f; } v; v.u = ((unsigned)u) << 16;
  return v.f;
}

__device__ __forceinline__ void async16(const void* g, void* l){
  __builtin_amdgcn_global_load_lds((__attribute__((address_space(1))) void*)g,
                                   (__attribute__((address_space(3))) void*)l, 16, 0, 0);
}

// ---- fused stage 1: count_edges(x4) + LN (1-pass, hoisted loads) + prep ----
__device__ __forceinline__ void tc_tile(const float* __restrict__ W,
                                        ushort_t* __restrict__ WT,
                                        int K, int Nn, int Kp, int bx, int by){
  __shared__ float tile[32][33];
  const int tx = threadIdx.x & 31, ty = threadIdx.x >> 5;
  const int k0 = bx*32, n0 = by*32;
  for (int i = ty; i < 32; i += 8){
    int k = k0 + i, n = n0 + tx;
    tile[i][tx] = (k < K && n < Nn) ? W[(size_t)k*Nn + n] : 0.f;
  }
  __syncthreads();
  for (int i = ty; i < 32; i += 8){
    int n = n0 + i, k = k0 + tx;
    if (n < Nn && k < Kp) WT[(size_t)n*Kp + k] = f2bf(tile[tx][i]);
  }
}

#define F1_CNT  782
#define F1_LN   (F1_CNT + 12500)
__global__ __launch_bounds__(256) void fused1(const float* __restrict__ x,
                                              const float* __restrict__ gw,
                                              const float* __restrict__ bw,
                                              ushort_t* __restrict__ xn,
                                              const int* __restrict__ ei,
                                              int* __restrict__ cnt,
                                              const float* W1, const float* Wr,
                                              const float* Wg, const float* W2,
                                              const float* b2, const float* br,
                                              ushort_t* W1T, ushort_t* WrgT,
                                              ushort_t* W2bf, float* b2rg){
  const int bid = blockIdx.x;
  if (bid < F1_CNT){
    int i4 = bid*256 + threadIdx.x;
    if (i4 < NE/4){
      int4v v = *(const int4v*)(ei + NE + i4*4);
      atomicAdd(&cnt[v.x], 1); atomicAdd(&cnt[v.y], 1);
      atomicAdd(&cnt[v.z], 1); atomicAdd(&cnt[v.w], 1);
    }
    return;
  }
  if (bid < F1_LN){
    const int wid = threadIdx.x >> 6, lane = threadIdx.x & 63;
    const int row = (bid - F1_CNT)*4 + wid;
    if (row >= NND) return;
    const float* xr = x + (size_t)row * DIN;
    // hoist ALL loads (x, gw, bw) before the reduction: 18-deep MLP
    f32x4 xa[3], xb[3], ga[3], gb[3], ba[3], bb[3];
    #pragma unroll
    for (int it = 0; it < 3; ++it){
      const int i = lane*8 + it*512;
      if (i < DIN){
        xa[it] = *(const f32x4*)(xr + i);
        xb[it] = *(const f32x4*)(xr + i + 4);
        ga[it] = *(const f32x4*)(gw + i);
        gb[it] = *(const f32x4*)(gw + i + 4);
        ba[it] = *(const f32x4*)(bw + i);
        bb[it] = *(const f32x4*)(bw + i + 4);
      } else {
        xa[it] = (f32x4){0.f,0.f,0.f,0.f};
        xb[it] = (f32x4){0.f,0.f,0.f,0.f};
        ga[it] = xa[it]; gb[it] = xa[it]; ba[it] = xa[it]; bb[it] = xa[it];
      }
    }
    float s = 0.f, sq = 0.f;
    #pragma unroll
    for (int it = 0; it < 3; ++it){
      s  += xa[it].x + xa[it].y + xa[it].z + xa[it].w
          + xb[it].x + xb[it].y + xb[it].z + xb[it].w;
      sq += xa[it].x*xa[it].x + xa[it].y*xa[it].y + xa[it].z*xa[it].z + xa[it].w*xa[it].w
          + xb[it].x*xb[it].x + xb[it].y*xb[it].y + xb[it].z*xb[it].z + xb[it].w*xb[it].w;
    }
    #pragma unroll
    for (int o = 32; o; o >>= 1){ s += __shfl_xor(s, o); sq += __shfl_xor(sq, o); }
    const float mu = s * (1.f/DIN);
    const float var = sq * (1.f/DIN) - mu*mu;
    const float rstd = rsqrtf(var + 1e-5f);
    ushort_t* xo = xn + (size_t)row * DINP;
    #pragma unroll
    for (int it = 0; it < 3; ++it){
      const int i = lane*8 + it*512;
      union { ushort_t u[8]; short8 v; } o;
      if (i < DIN){
        o.u[0] = f2bf((xa[it].x-mu)*rstd*ga[it].x + ba[it].x);
        o.u[1] = f2bf((xa[it].y-mu)*rstd*ga[it].y + ba[it].y);
        o.u[2] = f2bf((xa[it].z-mu)*rstd*ga[it].z + ba[it].z);
        o.u[3] = f2bf((xa[it].w-mu)*rstd*ga[it].w + ba[it].w);
        o.u[4] = f2bf((xb[it].x-mu)*rstd*gb[it].x + bb[it].x);
        o.u[5] = f2bf((xb[it].y-mu)*rstd*gb[it].y + bb[it].y);
        o.u[6] = f2bf((xb[it].z-mu)*rstd*gb[it].z + bb[it].z);
        o.u[7] = f2bf((xb[it].w-mu)*rstd*gb[it].w + bb[it].w);
      } else {
        o.u[0]=o.u[1]=o.u[2]=o.u[3]=o.u[4]=o.u[5]=o.u[6]=o.u[7]=0;
      }
      *(short8*)(xo + i) = o.v;
    }
    return;
  }
  {
    int b = bid - F1_LN;
    if (b < 1536){ tc_tile(W1, W1T, DIN, DHID, DINP, b % 48, b / 48); return; }
    b -= 1536;
    if (b < 128){ tc_tile(Wr, WrgT, DOUT, DHC, DOUT, b % 16, b / 16); return; }
    b -= 128;
    if (b < 128){ tc_tile(Wg, WrgT + 256*DOUT, DOUT, DHC, DOUT, b % 16, b / 16); return; }
    b -= 128;
    if (b < 256){
      const int idx = (b*256 + threadIdx.x)*8;
      f32x4 v0 = *(const f32x4*)(W2 + idx);
      f32x4 v1 = *(const f32x4*)(W2 + idx + 4);
      union { ushort_t u[8]; short8 s; } o;
      o.u[0]=f2bf(v0.x); o.u[1]=f2bf(v0.y); o.u[2]=f2bf(v0.z); o.u[3]=f2bf(v0.w);
      o.u[4]=f2bf(v1.x); o.u[5]=f2bf(v1.y); o.u[6]=f2bf(v1.z); o.u[7]=f2bf(v1.w);
      *(short8*)(W2bf + idx) = o.s;
      return;
    }
    b -= 256;
    {
      const int c = b*256 + threadIdx.x;
      float acc = 0.f;
      if (c < 256){
        for (int j = 0; j < DOUT; ++j) acc += b2[j]*Wr[(size_t)j*DHC + c];
        acc += br[c];
      } else {
        const int cc = c - 256;
        for (int j = 0; j < DOUT; ++j) acc += b2[j]*Wg[(size_t)j*DHC + cc];
      }
      b2rg[c] = acc;
      return;
    }
  }
}

// ------- 256x256 8-phase GEMM body (device fn; runtime act; bf16 out) -------
__device__ __forceinline__ void g256p8_body(ushort_t (&lds)[2][2][2][64*128],
                                            const ushort_t* __restrict__ A,
                                            const ushort_t* __restrict__ BT,
                                            const float* __restrict__ bias,
                                            ushort_t* __restrict__ out0,
                                            int M, int Nn, int K,
                                            int bid, int nwg, bool act){
  const int t = threadIdx.x, wid = t >> 6, lane = t & 63;
  const int CB = Nn >> 8;
  const int q = nwg >> 3, r = nwg & 7;
  const int xcd = bid & 7, slot = bid >> 3;
  const int lg = (xcd < r ? xcd*(q+1) : r*(q+1) + (xcd - r)*q) + slot;
  const int brow = (lg / CB) * 256, bcol = (lg % CB) * 256;

  const int l8  = t >> 3;
  const int cb  = (t & 7) << 4;
  const unsigned scb = (unsigned)(cb ^ ((l8 & 7) << 4));
  unsigned rowA[2][2], rowB[2][2];
  #pragma unroll
  for (int hf = 0; hf < 2; ++hf)
    #pragma unroll
    for (int rd = 0; rd < 2; ++rd){
      int ra = brow + hf*128 + rd*64 + l8; ra = ra < M ? ra : M-1;
      int rb = bcol + hf*128 + rd*64 + l8; rb = rb < Nn ? rb : Nn-1;
      rowA[hf][rd] = (unsigned)ra * (unsigned)(K*2);
      rowB[hf][rd] = (unsigned)rb * (unsigned)(K*2);
    }
  const int w8 = wid * 8;

#define STG_A(buf, hf, kt) do {                                               \
    const unsigned _ob = (unsigned)(kt)*128u + scb;                           \
    async16((const char*)A + rowA[hf][0] + _ob, &lds[buf][0][hf][(w8)*64]);   \
    async16((const char*)A + rowA[hf][1] + _ob, &lds[buf][0][hf][(64+w8)*64]);\
  } while(0)
#define STG_B(buf, hf, kt) do {                                               \
    const unsigned _ob = (unsigned)(kt)*128u + scb;                           \
    async16((const char*)BT + rowB[hf][0] + _ob, &lds[buf][1][hf][(w8)*64]);  \
    async16((const char*)BT + rowB[hf][1] + _ob, &lds[buf][1][hf][(64+w8)*64]);\
  } while(0)

  f32x4 acc[8][4];
  #pragma unroll
  for (int i=0;i<8;i++)
    #pragma unroll
    for (int j=0;j<4;j++) acc[i][j] = (f32x4){0.f,0.f,0.f,0.f};

  const int wrow = (wid >> 2), wcol = (wid & 3);
  const int fr = lane & 15;
  const int kb0 = (lane >> 4) << 4;
  const int sx  = (fr & 7) << 4;
  const int ko0 = ((kb0      ) ^ sx) >> 1;
  const int ko1 = ((kb0 | 64 ) ^ sx) >> 1;
  const int bhalf = wcol >> 1, brl = (wcol & 1)*64;

#define RD_A(buf, m) do {                                          \
    const int _ra = ((m)*16 + fr)*64;                              \
    af[m][0] = *(const short8*)&lds[buf][0][wrow][_ra + ko0];      \
    af[m][1] = *(const short8*)&lds[buf][0][wrow][_ra + ko1];      \
  } while(0)
#define RD_B(buf, n) do {                                          \
    const int _rb = (brl + (n)*16 + fr)*64;                        \
    bf[n][0] = *(const short8*)&lds[buf][1][bhalf][_rb + ko0];     \
    bf[n][1] = *(const short8*)&lds[buf][1][bhalf][_rb + ko1];     \
  } while(0)
#define SYNC_PH() do {                                             \
    __builtin_amdgcn_s_barrier();                                  \
    asm volatile("s_waitcnt lgkmcnt(0)" ::: "memory");             \
    __builtin_amdgcn_sched_barrier(0);                             \
  } while(0)
#define MFMA_Q(M0, N0) do {                                        \
    __builtin_amdgcn_s_setprio(1);                                 \
    _Pragma("unroll")                                              \
    for (int _m=(M0); _m<(M0)+4; ++_m)                             \
      _Pragma("unroll")                                            \
      for (int _n=(N0); _n<(N0)+2; ++_n){                          \
        acc[_m][_n] = __builtin_amdgcn_mfma_f32_16x16x32_bf16(af[_m][0], bf[_n][0], acc[_m][_n], 0, 0, 0); \
        acc[_m][_n] = __builtin_amdgcn_mfma_f32_16x16x32_bf16(af[_m][1], bf[_n][1], acc[_m][_n], 0, 0, 0); \
      }                                                            \
    __builtin_amdgcn_s_setprio(0);                                 \
  } while(0)

  const int nk = K >> 6;
  STG_A(0,0,0); STG_A(0,1,0); STG_B(0,0,0); STG_B(0,1,0);
  STG_A(1,0,1); STG_A(1,1,1);
  asm volatile("s_waitcnt vmcnt(4)" ::: "memory");
  __builtin_amdgcn_s_barrier();

  for (int kt = 0; kt < nk; ++kt){
    const int buf = kt & 1, obuf = buf ^ 1;
    short8 af[8][2], bf[4][2];
    RD_A(buf,0); RD_A(buf,1); RD_A(buf,2); RD_A(buf,3);
    RD_B(buf,0); RD_B(buf,1);
    if (kt + 1 < nk) STG_B(obuf, 0, kt + 1);
    SYNC_PH();
    MFMA_Q(0, 0);
    RD_A(buf,4); RD_A(buf,5); RD_A(buf,6); RD_A(buf,7);
    if (kt + 1 < nk) STG_B(obuf, 1, kt + 1);
    SYNC_PH();
    MFMA_Q(4, 0);
    RD_B(buf,2); RD_B(buf,3);
    if (kt + 2 < nk) STG_A(buf, 0, kt + 2);
    SYNC_PH();
    MFMA_Q(0, 2);
    if (kt + 2 < nk){
      STG_A(buf, 1, kt + 2);
      asm volatile("s_waitcnt vmcnt(4)" ::: "memory");
    } else {
      asm volatile("s_waitcnt vmcnt(0)" ::: "memory");
    }
    __builtin_amdgcn_s_barrier();
    MFMA_Q(4, 2);
  }
#undef STG_A
#undef STG_B
#undef RD_A
#undef RD_B
#undef SYNC_PH
#undef MFMA_Q

  float bv[4];
  #pragma unroll
  for (int n=0;n<4;n++){
    const int col = bcol + wcol*64 + n*16 + (lane & 15);
    bv[n] = bias ? bias[col] : 0.f;
  }
  ushort_t* sB = (ushort_t*)&lds[0][0][0][0];
  __syncthreads();
  #pragma unroll
  for (int m=0;m<8;m++){
    const int row = wrow*128 + m*16 + (lane >> 4)*4;
    #pragma unroll
    for (int n=0;n<4;n++){
      const int col = wcol*64 + n*16 + (lane & 15);
      #pragma unroll
      for (int j=0;j<4;j++){
        float v = acc[m][n][j] + bv[n];
        if (act) v = v > 0.f ? v : 0.f;
        sB[(row+j)*256 + col] = f2bf(v);
      }
    }
  }
  __syncthreads();
  const int srow = t >> 5, scol8 = (t & 31) * 8;
  #pragma unroll
  for (int rr = 0; rr < 16; ++rr){
    const int rloc = rr*16 + srow;
    const int grow = brow + rloc;
    if (grow < M)
      *(short8*)(out0 + (size_t)grow*Nn + bcol + scol8) = *(const short8*)&sB[rloc*256 + scol8];
  }
}

// ---- k2 mega kernel: scan (blk 0) + WcT tiny GEMM (blk 1-8) + GEMM1 --------
__global__ __launch_bounds__(512, 1) void mega_gemm(const ushort_t* __restrict__ xn,
                                                    const ushort_t* __restrict__ W1T,
                                                    const float* __restrict__ b1,
                                                    ushort_t* __restrict__ h1,
                                                    const ushort_t* __restrict__ WrgT,
                                                    const ushort_t* __restrict__ W2bf,
                                                    ushort_t* __restrict__ WcT,
                                                    const int* __restrict__ cnt,
                                                    int* __restrict__ offs,
                                                    int* __restrict__ cur){
  __shared__ __align__(16) ushort_t lds[2][2][2][64*128];  // 128 KiB
  const int t = threadIdx.x;

  if (blockIdx.x == 0){
    int* sbuf = (int*)&lds[0][0][0][0];
    const int chunk = (NND + 255) >> 8;                  // 196, mult of 4
    int s = 0;
    if (t < 256){
      const int s0 = t*chunk;
      const int s1 = (s0 + chunk < NND) ? s0 + chunk : NND;
      for (int i = s0; i < s1; i += 4){
        int4v v = *(const int4v*)(cnt + i);
        s += v.x + v.y + v.z + v.w + 4;
      }
    }
    sbuf[t] = s; __syncthreads();
    for (int o = 1; o < 256; o <<= 1){
      int xv = (t >= o && t < 256) ? sbuf[t-o] : 0;
      __syncthreads();
      if (t < 256) sbuf[t] += xv;
      __syncthreads();
    }
    if (t < 256){
      int run = sbuf[t] - s;
      const int s0 = t*chunk;
      const int s1 = (s0 + chunk < NND) ? s0 + chunk : NND;
      for (int i = s0; i < s1; i += 4){
        int4v v = *(const int4v*)(cnt + i);
        int4v cu;
        cu.x = run; run += v.x + 1;
        cu.y = run; run += v.y + 1;
        cu.z = run; run += v.z + 1;
        cu.w = run; run += v.w + 1;
        *(int4v*)(cur + i)  = cu;
        *(int4v*)(offs + i) = cu;
      }
      if (t == 255) offs[NND] = run;
    }
    return;
  }
  if (blockIdx.x < 9){
    g256p8_body(lds, WrgT, W2bf, nullptr, WcT, 512, 1024, 512,
                (int)blockIdx.x - 1, 8, false);
    return;
  }
  g256p8_body(lds, xn, W1T, b1, h1, NND, DHID, DINP,
              (int)blockIdx.x - 9, (int)gridDim.x - 9, true);
}

// ---- k3: 8-phase GEMM [res|gm] = h1 @ WcT^T + b2rg, bf16 split + att -------
#define G3_NWG 392
__global__ __launch_bounds__(512, 1) void gemm3p8(const ushort_t* __restrict__ A,
                                                  const ushort_t* __restrict__ BT,
                                                  const float* __restrict__ bias,
                                                  ushort_t* __restrict__ res,
                                                  ushort_t* __restrict__ gm,
                                                  const int* __restrict__ ei,
                                                  int* __restrict__ cur,
                                                  int* __restrict__ eidx,
                                                  const float* __restrict__ att_s,
                                                  const float* __restrict__ att_d,
                                                  float* __restrict__ asrc,
                                                  float* __restrict__ adst){
  __shared__ __align__(16) ushort_t lds[2][2][2][64*128];  // 128 KiB
  const int t = threadIdx.x, wid = t >> 6, lane = t & 63;

  if (blockIdx.x >= G3_NWG){
    int i = (blockIdx.x - G3_NWG)*512 + t;
    if (i < NND){
      int p = atomicAdd(&cur[i], 1); eidx[p] = i;
    } else if (i < NND + NE){
      int e = i - NND;
      int src = ei[e], dst = ei[NE + e];
      int p = atomicAdd(&cur[dst], 1);
      eidx[p] = src;
    }
    return;
  }

  const int M = NND, Nn = 512, K = DHID;
  const int bid = blockIdx.x, nwg = G3_NWG;
  const int CB = 2;
  const int q = nwg >> 3, r = nwg & 7;
  const int xcd = bid & 7, slot = bid >> 3;
  const int lg = (xcd < r ? xcd*(q+1) : r*(q+1) + (xcd - r)*q) + slot;
  const int brow = (lg / CB) * 256, bcol = (lg % CB) * 256;

  const int l8  = t >> 3;
  const int cb  = (t & 7) << 4;
  const unsigned scb = (unsigned)(cb ^ ((l8 & 7) << 4));
  unsigned rowA[2][2], rowB[2][2];
  #pragma unroll
  for (int hf = 0; hf < 2; ++hf)
    #pragma unroll
    for (int rd = 0; rd < 2; ++rd){
      int ra = brow + hf*128 + rd*64 + l8; ra = ra < M ? ra : M-1;
      int rb = bcol + hf*128 + rd*64 + l8; rb = rb < Nn ? rb : Nn-1;
      rowA[hf][rd] = (unsigned)ra * (unsigned)(K*2);
      rowB[hf][rd] = (unsigned)rb * (unsigned)(K*2);
    }
  const int w8 = wid * 8;

#define STG_A(buf, hf, kt) do {                                               \
    const unsigned _ob = (unsigned)(kt)*128u + scb;                           \
    async16((const char*)A + rowA[hf][0] + _ob, &lds[buf][0][hf][(w8)*64]);   \
    async16((const char*)A + rowA[hf][1] + _ob, &lds[buf][0][hf][(64+w8)*64]);\
  } while(0)
#define STG_B(buf, hf, kt) do {                                               \
    const unsigned _ob = (unsigned)(kt)*128u + scb;                           \
    async16((const char*)BT + rowB[hf][0] + _ob, &lds[buf][1][hf][(w8)*64]);  \
    async16((const char*)BT + rowB[hf][1] + _ob, &lds[buf][1][hf][(64+w8)*64]);\
  } while(0)

  f32x4 acc[8][4];
  #pragma unroll
  for (int i=0;i<8;i++)
    #pragma unroll
    for (int j=0;j<4;j++) acc[i][j] = (f32x4){0.f,0.f,0.f,0.f};

  const int wrow = (wid >> 2), wcol = (wid & 3);
  const int fr = lane & 15;
  const int kb0 = (lane >> 4) << 4;
  const int sx  = (fr & 7) << 4;
  const int ko0 = ((kb0      ) ^ sx) >> 1;
  const int ko1 = ((kb0 | 64 ) ^ sx) >> 1;
  const int bhalf = wcol >> 1, brl = (wcol & 1)*64;

#define RD_A(buf, m) do {                                          \
    const int _ra = ((m)*16 + fr)*64;                              \
    af[m][0] = *(const short8*)&lds[buf][0][wrow][_ra + ko0];      \
    af[m][1] = *(const short8*)&lds[buf][0][wrow][_ra + ko1];      \
  } while(0)
#define RD_B(buf, n) do {                                          \
    const int _rb = (brl + (n)*16 + fr)*64;                        \
    bf[n][0] = *(const short8*)&lds[buf][1][bhalf][_rb + ko0];     \
    bf[n][1] = *(const short8*)&lds[buf][1][bhalf][_rb + ko1];     \
  } while(0)
#define SYNC_PH() do {                                             \
    __builtin_amdgcn_s_barrier();                                  \
    asm volatile("s_waitcnt lgkmcnt(0)" ::: "memory");             \
    __builtin_amdgcn_sched_barrier(0);                             \
  } while(0)
#define MFMA_Q(M0, N0) do {                                        \
    __builtin_amdgcn_s_setprio(1);                                 \
    _Pragma("unroll")                                              \
    for (int _m=(M0); _m<(M0)+4; ++_m)                             \
      _Pragma("unroll")                                            \
      for (int _n=(N0); _n<(N0)+2; ++_n){                          \
        acc[_m][_n] = __builtin_amdgcn_mfma_f32_16x16x32_bf16(af[_m][0], bf[_n][0], acc[_m][_n], 0, 0, 0); \
        acc[_m][_n] = __builtin_amdgcn_mfma_f32_16x16x32_bf16(af[_m][1], bf[_n][1], acc[_m][_n], 0, 0, 0); \
      }                                                            \
    __builtin_amdgcn_s_setprio(0);                                 \
  } while(0)

  const int nk = K >> 6;
  STG_A(0,0,0); STG_A(0,1,0); STG_B(0,0,0); STG_B(0,1,0);
  STG_A(1,0,1); STG_A(1,1,1);
  asm volatile("s_waitcnt vmcnt(4)" ::: "memory");
  __builtin_amdgcn_s_barrier();

  for (int kt = 0; kt < nk; ++kt){
    const int buf = kt & 1, obuf = buf ^ 1;
    short8 af[8][2], bf[4][2];
    RD_A(buf,0); RD_A(buf,1); RD_A(buf,2); RD_A(buf,3);
    RD_B(buf,0); RD_B(buf,1);
    if (kt + 1 < nk) STG_B(obuf, 0, kt + 1);
    SYNC_PH();
    MFMA_Q(0, 0);
    RD_A(buf,4); RD_A(buf,5); RD_A(buf,6); RD_A(buf,7);
    if (kt + 1 < nk) STG_B(obuf, 1, kt + 1);
    SYNC_PH();
    MFMA_Q(4, 0);
    RD_B(buf,2); RD_B(buf,3);
    if (kt + 2 < nk) STG_A(buf, 0, kt + 2);
    SYNC_PH();
    MFMA_Q(0, 2);
    if (kt + 2 < nk){
      STG_A(buf, 1, kt + 2);
      asm volatile("s_waitcnt vmcnt(4)" ::: "memory");
    } else {
      asm volatile("s_waitcnt vmcnt(0)" ::: "memory");
    }
    __builtin_amdgcn_s_barrier();
    MFMA_Q(4, 2);
  }
#undef STG_A
#undef STG_B
#undef RD_A
#undef RD_B
#undef SYNC_PH
#undef MFMA_Q

  float bv[4];
  #pragma unroll
  for (int n=0;n<4;n++){
    const int col = bcol + wcol*64 + n*16 + (lane & 15);
    bv[n] = bias[col];
  }
  // unified bf16 epilogue: bcol==0 -> res (bf16); bcol==256 -> gm (+att)
  ushort_t* outB = (bcol == 0) ? res : gm;
  ushort_t* sB = (ushort_t*)&lds[0][0][0][0];      // [256][256] bf16
  __syncthreads();
  #pragma unroll
  for (int m=0;m<8;m++){
    const int row = wrow*128 + m*16 + (lane >> 4)*4;
    #pragma unroll
    for (int n=0;n<4;n++){
      const int col = wcol*64 + n*16 + (lane & 15);
      #pragma unroll
      for (int j=0;j<4;j++)
        sB[(row+j)*256 + col] = f2bf(acc[m][n][j] + bv[n]);
    }
  }
  __syncthreads();
  const int srow = t >> 5, scol8 = (t & 31) * 8;
  #pragma unroll
  for (int rr = 0; rr < 16; ++rr){
    const int rloc = rr*16 + srow;
    const int grow = brow + rloc;
    if (grow < M)
      *(short8*)(outB + (size_t)grow*256 + scol8) = *(const short8*)&sB[rloc*256 + scol8];
  }
  if (bcol != 0){
    const int h = t & 7;
    const int hc0 = h * 32;
    #pragma unroll
    for (int k = 0; k < 4; ++k){
      const int rloc = (t >> 3) + k*64;
      const int grow = brow + rloc;
      if (grow < M){
        float a = 0.f, d = 0.f;
        #pragma unroll
        for (int c0 = 0; c0 < 32; c0 += 8){
          short8 gv = *(const short8*)&sB[rloc*256 + hc0 + c0];
          #pragma unroll
          for (int j = 0; j < 8; ++j){
            float g = bf2f((ushort_t)gv[j]);
            a += g*att_s[hc0 + c0 + j];
            d += g*att_d[hc0 + c0 + j];
          }
        }
        asrc[grow*NHD + h] = a;
        adst[grow*NHD + h] = d;
      }
    }
  }
}

// ---- fused GAT aggregate (wave/node, 8-edge chunks, 2-deep pipeline) ------
__global__ __launch_bounds__(256) void gat_agg(const int* __restrict__ offs,
                                               const int* __restrict__ eidx,
                                               const float* __restrict__ asrc,
                                               const float* __restrict__ adst,
                                               const ushort_t* __restrict__ gm,
                                               const ushort_t* __restrict__ res,
                                               const float* __restrict__ bg,
                                               float* __restrict__ out){
  const int wid = threadIdx.x >> 6, lane = threadIdx.x & 63;
  const int node = blockIdx.x*4 + wid;
  if (node >= NND) return;
  const int h = lane >> 3, jj = lane & 7;
  const int e0 = offs[node], deg = offs[node+1] - e0;
  const float adv = adst[node*NHD + h];

  float mx = -1e30f;
  for (int j = jj; j < deg; j += 8){
    int s = eidx[e0 + j];
    float e = asrc[s*NHD + h] + adv; e = e > 0.f ? e : 0.2f*e;
    mx = fmaxf(mx, e);
  }
  mx = fmaxf(mx, __shfl_xor(mx, 1));
  mx = fmaxf(mx, __shfl_xor(mx, 2));
  mx = fmaxf(mx, __shfl_xor(mx, 4));

  const int c4 = lane*4;
  float sm = 0.f;
  f32x4 acc = {0.f,0.f,0.f,0.f};

  int s = 0; float w = 0.f;
  {
    const int cnt0 = deg < 8 ? deg : 8;
    if (jj < cnt0){
      s = eidx[e0 + jj];
      float e = asrc[s*NHD + h] + adv; e = e > 0.f ? e : 0.2f*e;
      w = __expf(e - mx);
      sm += w;
    }
  }
  for (int j0 = 0; j0 < deg; j0 += 8){
    const int cnt = (deg - j0) < 8 ? (deg - j0) : 8;
    int ns = 0; float nw = 0.f;
    const int ncnt = (deg - j0 - 8) < 8 ? (deg - j0 - 8) : 8;
    if (jj < ncnt){
      ns = eidx[e0 + j0 + 8 + jj];
      float e = asrc[ns*NHD + h] + adv; e = e > 0.f ? e : 0.2f*e;
      nw = __expf(e - mx);
      sm += nw;
    }
    #pragma unroll
    for (int u = 0; u < 8; ++u){
      if (u < cnt){
        const int   su = __builtin_amdgcn_readlane(s, u);
        const float wu = __shfl(w, (h << 3) | u);
        short4v gv = *(const short4v*)(gm + (size_t)su*DHC + c4);
        acc.x += wu*bf2f((ushort_t)gv.x);
        acc.y += wu*bf2f((ushort_t)gv.y);
        acc.z += wu*bf2f((ushort_t)gv.z);
        acc.w += wu*bf2f((ushort_t)gv.w);
      }
    }
    s = ns; w = nw;
  }
  sm += __shfl_xor(sm, 1); sm += __shfl_xor(sm, 2); sm += __shfl_xor(sm, 4);
  const float inv = 1.f/(sm + 1e-16f);

  f32x4 bgv = *(const f32x4*)(bg + c4);
  short4v rv4 = *(const short4v*)(res + (size_t)node*DHC + c4);
  f32x4 o;
  #pragma unroll
  for (int qq = 0; qq < 4; ++qq){
    float v = acc[qq]*inv + bgv[qq];
    v = v > 0.f ? v : expm1f(v);
    o[qq] = v + bf2f((ushort_t)rv4[qq]);
  }
  *(f32x4*)(out + (size_t)node*DHC + c4) = o;
}

extern "C" void kernel_launch(void* const* d_in, const int* in_sizes, int n_in,
                              void* d_out, int out_size, void* d_ws, size_t ws_size,
                              hipStream_t stream){
  (void)in_sizes; (void)n_in; (void)out_size; (void)ws_size;
  const float* x     = (const float*)d_in[0];
  const int*   ei    = (const int*)d_in[1];
  const float* ln_g  = (const float*)d_in[2];
  const float* ln_b  = (const float*)d_in[3];
  const float* W1    = (const float*)d_in[4];
  const float* b1    = (const float*)d_in[5];
  const float* W2    = (const float*)d_in[6];
  const float* b2    = (const float*)d_in[7];
  const float* Wr    = (const float*)d_in[8];
  const float* br    = (const float*)d_in[9];
  const float* Wg    = (const float*)d_in[10];
  const float* att_s = (const float*)d_in[11];
  const float* att_d = (const float*)d_in[12];
  const float* bg    = (const float*)d_in[13];
  float* out = (float*)d_out;

  char* p = (char*)d_ws;
  ushort_t* xn   = (ushort_t*)(p);                   // [0, 153,600,000)
  ushort_t* h1   = (ushort_t*)(p + 153600000);       // -> 256,000,000
  float*    asrc = (float*)(p + 256000000);
  float*    adst = (float*)(p + 257600000);
  int*      cnt  = (int*)(p + 259200000);
  int*      offs = (int*)(p + 259400064);
  int*      cur  = (int*)(p + 259600128);
  int*      eidx = (int*)(p + 259800192);            // -> 263,200,192
  ushort_t* W1T  = (ushort_t*)d_out;                           // 3,145,728
  ushort_t* WrgT = (ushort_t*)((char*)d_out + 3145728);        //   524,288
  ushort_t* W2bf = (ushort_t*)((char*)d_out + 3670016);        // 1,048,576
  ushort_t* WcT  = (ushort_t*)((char*)d_out + 4718592);        // 1,048,576
  float*    b2rg = (float*)((char*)d_out + 5767168);           //     2,048
  // aliased into xn region (xn dead after k2)
  ushort_t* res  = (ushort_t*)(p + 0);               //  25,600,000 (bf16)
  ushort_t* gm   = (ushort_t*)(p + 51200000);        //  25,600,000 (bf16)

  // k0: zero edge counters (DMA)
  hipMemsetAsync(cnt, 0, NND*sizeof(int), stream);

  // k1: fused count_edges(x4) + LN (1-pass, hoisted loads) + weight prep
  fused1<<<F1_LN + 2050, 256, 0, stream>>>(
      x, ln_g, ln_b, xn, ei, cnt,
      W1, Wr, Wg, W2, b2, br, W1T, WrgT, W2bf, b2rg);

  // k2: scan (blk 0) + WcT tiny GEMM (blk 1-8) + GEMM1 8-phase (784 blks)
  mega_gemm<<<793, 512, 0, stream>>>(xn, W1T, b1, h1, WrgT, W2bf, WcT,
                                     cnt, offs, cur);

  // k3: 8-phase fused [res|gm] = h1 @ WcT^T + b2rg (bf16 split + att + fill)
  gemm3p8<<<G3_NWG + (NND + NE + 511)/512, 512, 0, stream>>>(
      h1, WcT, b2rg, res, gm,
      ei, cur, eidx, att_s, att_d, asrc, adst);

  // k4: GAT aggregate
  gat_agg<<<(NND + 3)/4, 256, 0, stream>>>(offs, eidx, asrc, adst, gm, res, bg, out);
}